// Round 1
// baseline (1191.229 us; speedup 1.0000x reference)
//
#include <hip/hip_runtime.h>

typedef __attribute__((ext_vector_type(8))) short short8;
typedef __attribute__((ext_vector_type(4))) float f32x4;
typedef __attribute__((ext_vector_type(4))) unsigned short us4;

#define DEV static __device__ __forceinline__

constexpr int QLEN = 2048;
constexpr int DMODEL = 4096;
constexpr int NHEAD = 32;
constexpr int NKV = 8;
constexpr int HD = 128;
constexpr int NSINK = 4;
constexpr int NWIN = 2048;
constexpr int CUR0 = NSINK + NWIN;     // 2052
constexpr int KTOT = CUR0 + QLEN;      // 4100
constexpr int KT_PAD = 4224;           // 66 * 64
constexpr float LOG2E = 1.4426950408889634f;
constexpr float NEGBIG = -1.0e30f;
constexpr float QSCALE = 0.08838834764831843f * LOG2E; // 1/sqrt(128) * log2(e)

DEV unsigned short f2bf(float f) {
  unsigned int u = __float_as_uint(f);
  u += 0x7fffu + ((u >> 16) & 1u);
  return (unsigned short)(u >> 16);
}

DEV void gld16(const void* g, void* l) {
  __builtin_amdgcn_global_load_lds((const __attribute__((address_space(1))) void*)g,
                                   (__attribute__((address_space(3))) void*)l, 16, 0, 0);
}

// ---------------- small prep kernels ----------------

__global__ void maxpos_kernel(const int* __restrict__ sp, const int* __restrict__ kp,
                              int* __restrict__ outp) {
  __shared__ int red[256];
  int t = threadIdx.x;
  int m = -0x7fffffff;
  for (int i = t; i < NSINK; i += 256) m = max(m, sp[i]);
  for (int i = t; i < NWIN; i += 256) m = max(m, kp[i]);
  red[t] = m;
  __syncthreads();
  for (int s = 128; s > 0; s >>= 1) {
    if (t < s) red[t] = max(red[t], red[t + s]);
    __syncthreads();
  }
  if (t == 0) outp[0] = red[0] + 1;
}

__global__ void bias_kernel(const float* __restrict__ sm, const float* __restrict__ km,
                            float* __restrict__ bias) {
  int kk = blockIdx.x * 256 + threadIdx.x;
  if (kk >= KT_PAD) return;
  float b;
  if (kk < NSINK) b = sm[kk] * NEGBIG;
  else if (kk < CUR0) b = km[kk - NSINK] * NEGBIG;
  else if (kk < KTOT) b = 0.0f;
  else b = NEGBIG;
  bias[kk] = b * LOG2E;
}

__global__ __launch_bounds__(256) void cvt_kernel(const float* __restrict__ src,
                                                  unsigned short* __restrict__ dst) {
  long i = ((long)blockIdx.x * 256 + threadIdx.x) * 4;
  f32x4 v = *(const f32x4*)(src + i);
  us4 o;
  o[0] = f2bf(v[0]); o[1] = f2bf(v[1]); o[2] = f2bf(v[2]); o[3] = f2bf(v[3]);
  *(us4*)(dst + i) = o;
}

// W [K][N] f32 -> WT [N][K] bf16
__global__ void transpose_cvt(const float* __restrict__ W, unsigned short* __restrict__ WT,
                              int K, int N) {
  __shared__ float t[32][33];
  int n0 = blockIdx.x * 32, k0 = blockIdx.y * 32;
  int tx = threadIdx.x, ty = threadIdx.y;
  for (int p = 0; p < 4; p++) {
    int k = k0 + ty + p * 8;
    t[ty + p * 8][tx] = W[(long)k * N + n0 + tx];
  }
  __syncthreads();
  for (int p = 0; p < 4; p++) {
    int n = n0 + ty + p * 8;
    WT[(long)n * K + k0 + tx] = f2bf(t[tx][ty + p * 8]);
  }
}

// ---------------- GEMM: C[M][N] f32 = A[M][K] bf16 @ Bt[N][K] bf16 ----------------
// 128x128 tile, BK=64, global_load_lds width16, XOR-swizzled LDS (2-way max)
__global__ __launch_bounds__(256) void gemm_bt(const unsigned short* __restrict__ A,
                                               const unsigned short* __restrict__ Bt,
                                               float* __restrict__ C,
                                               int M, int N, int K) {
  __shared__ __align__(16) unsigned short As[128 * 64];
  __shared__ __align__(16) unsigned short Bs[128 * 64];
  int tid = threadIdx.x, lane = tid & 63, w = tid >> 6;
  int m0 = blockIdx.y * 128, n0 = blockIdx.x * 128;
  int wm = w & 1, wn = w >> 1;
  f32x4 z = {0.f, 0.f, 0.f, 0.f};
  f32x4 acc[4][4];
  for (int i = 0; i < 4; i++) for (int j = 0; j < 4; j++) acc[i][j] = z;
  int nK = K >> 6;
  for (int ks = 0; ks < nK; ks++) {
    long k0 = (long)ks << 6;
    for (int t = 0; t < 4; t++) {
      int chunk = w * 4 + t;
      int row = chunk * 8 + (lane >> 3);
      int kb = lane & 7;
      int kbs = kb ^ (row & 7);
      gld16(A + ((long)(m0 + row) * K + k0 + kbs * 8), &As[chunk * 512 + lane * 8]);
      gld16(Bt + ((long)(n0 + row) * K + k0 + kbs * 8), &Bs[chunk * 512 + lane * 8]);
    }
    __syncthreads();
    for (int kc = 0; kc < 2; kc++) {
      short8 af[4], bf[4];
      int c = kc * 4 + (lane >> 4);
      for (int i = 0; i < 4; i++) {
        int ra = wm * 64 + i * 16 + (lane & 15);
        af[i] = *(const short8*)&As[ra * 64 + (c ^ (ra & 7)) * 8];
        int rb = wn * 64 + i * 16 + (lane & 15);
        bf[i] = *(const short8*)&Bs[rb * 64 + (c ^ (rb & 7)) * 8];
      }
      for (int i = 0; i < 4; i++)
        for (int j = 0; j < 4; j++)
          acc[i][j] = __builtin_amdgcn_mfma_f32_16x16x32_bf16(af[i], bf[j], acc[i][j], 0, 0, 0);
    }
    __syncthreads();
  }
  for (int i = 0; i < 4; i++) {
    int m = m0 + wm * 64 + i * 16 + ((lane >> 4) << 2);
    for (int j = 0; j < 4; j++) {
      int n = n0 + wn * 64 + j * 16 + (lane & 15);
      float* cp = C + (long)m * N + n;
      for (int r = 0; r < 4; r++) cp[(long)r * N] = acc[i][j][r];
    }
  }
}

// ---------------- RoPE + scatter (writes bf16, k-contiguous dst) ----------------
// dst[h][dstPos0 + s][d] = rope(src[h*hStride + s*sStride + d], pos) * scale
__global__ void rope_scatter(const float* __restrict__ src, long sStride, long hStride,
                             const int* __restrict__ posArr, const int* __restrict__ maxp,
                             unsigned short* __restrict__ dst, long dstHStride, int dstPos0,
                             float scale) {
  int s = blockIdx.x, h = blockIdx.y, d = threadIdx.x;
  int pos = posArr ? posArr[s] : (maxp[0] + s);
  const float* row = src + (long)h * hStride + (long)s * sStride;
  float x = row[d];
  float x2 = row[d ^ 64];
  float rot = (d < 64) ? -x2 : x2;
  int i = d & 63;
  float invf = exp2f(-(float)(2 * i) * (13.287712379549449f / 128.0f));
  float ang = (float)pos * invf;
  float c = cosf(ang), sn = sinf(ang);
  float val = (x * c + rot * sn) * scale;
  dst[(long)h * dstHStride + (long)(dstPos0 + s) * HD + d] = f2bf(val);
}

// V scatter with transpose: VT[(kvh*128 + d)*KT_PAD + dstPos0 + s] = bf16(src)
__global__ void scatter_vt(const float* __restrict__ src, long sStride, long hStride,
                           unsigned short* __restrict__ VT, int dstPos0, int S) {
  __shared__ float t[32][33];
  int kvh = blockIdx.z, d0 = blockIdx.y * 32, s0 = blockIdx.x * 32;
  int tx = threadIdx.x, ty = threadIdx.y;
  for (int p = 0; p < 4; p++) {
    int s = s0 + ty + p * 8;
    if (s < S) t[ty + p * 8][tx] = src[(long)kvh * hStride + (long)s * sStride + d0 + tx];
  }
  __syncthreads();
  for (int p = 0; p < 4; p++) {
    int d = d0 + ty + p * 8;
    int s = s0 + tx;
    if (s < S)
      VT[((long)kvh * HD + d) * KT_PAD + dstPos0 + s] = f2bf(t[tx][ty + p * 8]);
  }
}

__global__ void pad_zero(unsigned short* __restrict__ Kb, unsigned short* __restrict__ VTb) {
  int idx = blockIdx.x * 256 + threadIdx.x;
  int total = NKV * (KT_PAD - KTOT) * HD;
  if (idx >= total) return;
  int per = (KT_PAD - KTOT) * HD;
  int kvh = idx / per;
  int rem = idx % per;
  int pos = KTOT + rem / HD;
  int d = rem % HD;
  Kb[((long)kvh * KT_PAD + pos) * HD + d] = 0;
  VTb[((long)kvh * HD + d) * KT_PAD + pos] = 0;
}

// ---------------- flash attention ----------------
// grid (16 q-tiles, 32 heads), 256 thr. Per wave: 32 q rows. BK=64.
__global__ __launch_bounds__(256) void attn_kernel(
    const unsigned short* __restrict__ Qb,   // [32][2048][128], pre-scaled by QSCALE
    const unsigned short* __restrict__ Kb,   // [8][KT_PAD][128]
    const unsigned short* __restrict__ VTb,  // [8][128][KT_PAD]
    const float* __restrict__ biasArr,       // [KT_PAD], already * LOG2E
    unsigned short* __restrict__ attnOut) {  // [2048][4096]
  __shared__ __align__(16) unsigned short Kt[64 * 128];   // [pos][d]
  __shared__ __align__(16) unsigned short Vt[128 * 64];   // [d][pos]
  __shared__ __align__(16) unsigned short Pt[4][32 * 72]; // per-wave [row][64+8pad]
  int tid = threadIdx.x, lane = tid & 63, w = tid >> 6;
  int q0 = blockIdx.x * 128;
  int h = blockIdx.y, kvh = h >> 2;
  int wq0 = q0 + w * 32;

  short8 qf[2][4];
  for (int i = 0; i < 2; i++)
    for (int kc = 0; kc < 4; kc++) {
      long off = ((long)h * QLEN + wq0 + i * 16 + (lane & 15)) * HD + kc * 32 + (lane >> 4) * 8;
      qf[i][kc] = *(const short8*)(Qb + off);
    }

  f32x4 z = {0.f, 0.f, 0.f, 0.f};
  f32x4 o[2][8];
  for (int i = 0; i < 2; i++) for (int j = 0; j < 8; j++) o[i][j] = z;
  float mrun[2][4], lrun[2][4];
  for (int i = 0; i < 2; i++) for (int r = 0; r < 4; r++) { mrun[i][r] = -INFINITY; lrun[i][r] = 0.f; }

  int nsteps = min(KT_PAD / 64, (CUR0 + q0 + 127) / 64 + 1);
  const unsigned short* Kbase = Kb + (long)kvh * KT_PAD * HD;
  const unsigned short* Vbase = VTb + (long)kvh * HD * KT_PAD;

  for (int st = 0; st < nsteps; st++) {
    long k0 = (long)st * 64;
    for (int t = 0; t < 4; t++) {
      int chunk = w * 4 + t;
      { // K tile rows = 256B (16 chunks of 16B)
        int row = chunk * 4 + (lane >> 4);
        int kb = lane & 15;
        int kbs = kb ^ (row & 15);
        gld16(Kbase + (k0 + row) * HD + kbs * 8, &Kt[chunk * 512 + lane * 8]);
      }
      { // V tile rows = 128B (8 chunks)
        int row = chunk * 8 + (lane >> 3);
        int kb = lane & 7;
        int kbs = kb ^ (row & 7);
        gld16(Vbase + (long)row * KT_PAD + k0 + kbs * 8, &Vt[chunk * 512 + lane * 8]);
      }
    }
    __syncthreads();

    // S = Q @ K^T   (already in log2 units, bias already in log2 units)
    f32x4 s[2][4];
    for (int j = 0; j < 4; j++) {
      f32x4 a0 = z, a1 = z;
      int row = j * 16 + (lane & 15);
      for (int kc = 0; kc < 4; kc++) {
        int c = kc * 4 + (lane >> 4);
        short8 b = *(const short8*)&Kt[row * 128 + (c ^ (row & 15)) * 8];
        a0 = __builtin_amdgcn_mfma_f32_16x16x32_bf16(qf[0][kc], b, a0, 0, 0, 0);
        a1 = __builtin_amdgcn_mfma_f32_16x16x32_bf16(qf[1][kc], b, a1, 0, 0, 0);
      }
      s[0][j] = a0; s[1][j] = a1;
    }

    float bj[4];
    for (int j = 0; j < 4; j++) bj[j] = biasArr[k0 + j * 16 + (lane & 15)];

    for (int i = 0; i < 2; i++) {
      for (int r = 0; r < 4; r++) {
        int qrow = wq0 + i * 16 + ((lane >> 4) << 2) + r;
        float mloc = -3.0e38f;
        for (int j = 0; j < 4; j++) {
          float v = s[i][j][r] + bj[j];
          int col = (int)k0 + j * 16 + (lane & 15);
          if (col > qrow + CUR0) v = -1.0e30f;  // causal
          s[i][j][r] = v;
          mloc = fmaxf(mloc, v);
        }
        for (int off = 1; off < 16; off <<= 1) mloc = fmaxf(mloc, __shfl_xor(mloc, off, 64));
        float mnew = fmaxf(mrun[i][r], mloc);
        float alpha = exp2f(mrun[i][r] - mnew);
        mrun[i][r] = mnew;
        float psum = 0.f;
        int prow = i * 16 + ((lane >> 4) << 2) + r;
        for (int j = 0; j < 4; j++) {
          float p = exp2f(s[i][j][r] - mnew);
          psum += p;
          Pt[w][prow * 72 + j * 16 + (lane & 15)] = f2bf(p);
        }
        for (int off = 1; off < 16; off <<= 1) psum += __shfl_xor(psum, off, 64);
        lrun[i][r] = lrun[i][r] * alpha + psum;
        for (int j = 0; j < 8; j++) o[i][j][r] *= alpha;
      }
    }

    // O += P @ V
    for (int kcp = 0; kcp < 2; kcp++) {
      short8 pf[2];
      for (int i = 0; i < 2; i++) {
        int row = i * 16 + (lane & 15);
        pf[i] = *(const short8*)&Pt[w][row * 72 + kcp * 32 + (lane >> 4) * 8];
      }
      for (int jd = 0; jd < 8; jd++) {
        int row = jd * 16 + (lane & 15);
        int c = kcp * 4 + (lane >> 4);
        short8 vfr = *(const short8*)&Vt[row * 64 + (c ^ (row & 7)) * 8];
        o[0][jd] = __builtin_amdgcn_mfma_f32_16x16x32_bf16(pf[0], vfr, o[0][jd], 0, 0, 0);
        o[1][jd] = __builtin_amdgcn_mfma_f32_16x16x32_bf16(pf[1], vfr, o[1][jd], 0, 0, 0);
      }
    }
    __syncthreads();
  }

  for (int i = 0; i < 2; i++) {
    for (int r = 0; r < 4; r++) {
      float inv = 1.0f / lrun[i][r];
      int qrow = wq0 + i * 16 + ((lane >> 4) << 2) + r;
      unsigned short* op = attnOut + (long)qrow * DMODEL + h * HD;
      for (int j = 0; j < 8; j++) op[j * 16 + (lane & 15)] = f2bf(o[i][j][r] * inv);
    }
  }
}

// ---------------- launcher ----------------
extern "C" void kernel_launch(void* const* d_in, const int* in_sizes, int n_in,
                              void* d_out, int out_size, void* d_ws, size_t ws_size,
                              hipStream_t stream) {
  (void)in_sizes; (void)n_in; (void)out_size; (void)ws_size;
  const float* hidden    = (const float*)d_in[0];
  const float* sink_k    = (const float*)d_in[1];
  const float* sink_v    = (const float*)d_in[2];
  const float* win_k     = (const float*)d_in[3];
  const float* win_v     = (const float*)d_in[4];
  const int*   sink_pos  = (const int*)d_in[5];
  const int*   key_pos   = (const int*)d_in[6];
  const float* sink_mask = (const float*)d_in[7];
  const float* key_mask  = (const float*)d_in[8];
  const float* Wq = (const float*)d_in[9];
  const float* Wk = (const float*)d_in[10];
  const float* Wv = (const float*)d_in[11];
  const float* Wo = (const float*)d_in[12];
  float* out = (float*)d_out;

  char* ws = (char*)d_ws;
  // region 0 [0, 16.8M): hidB (stages 2-5), later attn (stage 7+)
  unsigned short* hidB = (unsigned short*)(ws + 0);
  unsigned short* attn = (unsigned short*)(ws + 0);
  unsigned short* WoT  = (unsigned short*)(ws + 16777216L);
  // region R1 [50.3M, 100.7M): WqT|WkT|WvT (contiguous Bt, stages 4-5),
  // later Qb|Kb|VTb (stage 6+)
  unsigned short* WqT  = (unsigned short*)(ws + 50331648L);
  unsigned short* Qb   = (unsigned short*)(ws + 50331648L);
  unsigned short* Kb   = (unsigned short*)(ws + 50331648L + 16777216L);
  unsigned short* VTb  = (unsigned short*)(ws + 50331648L + 25427968L);
  unsigned short* WkT  = (unsigned short*)(ws + 50331648L + 33554432L);
  unsigned short* WvT  = (unsigned short*)(ws + 50331648L + 41943040L);
  float* qkvF = (float*)(ws + 100663296L);   // [2048][6144] f32
  float* bias = (float*)(ws + 150994944L);   // [KT_PAD] f32
  int*   maxp = (int*)(ws + 150994944L + 16896L);

  dim3 tb(32, 8);
  maxpos_kernel<<<1, 256, 0, stream>>>(sink_pos, key_pos, maxp);
  bias_kernel<<<(KT_PAD + 255) / 256, 256, 0, stream>>>(sink_mask, key_mask, bias);
  cvt_kernel<<<(QLEN * DMODEL / 4) / 256, 256, 0, stream>>>(hidden, hidB);
  transpose_cvt<<<dim3(128, 128), tb, 0, stream>>>(Wq, WqT, DMODEL, 4096);
  transpose_cvt<<<dim3(32, 128),  tb, 0, stream>>>(Wk, WkT, DMODEL, 1024);
  transpose_cvt<<<dim3(32, 128),  tb, 0, stream>>>(Wv, WvT, DMODEL, 1024);
  transpose_cvt<<<dim3(128, 128), tb, 0, stream>>>(Wo, WoT, DMODEL, 4096);

  // fused QKV projection: Bt = [WqT;WkT;WvT] (contiguous), N = 6144
  gemm_bt<<<dim3(48, 16), 256, 0, stream>>>(hidB, WqT, qkvF, QLEN, 6144, DMODEL);

  // RoPE + scatter (Q scaled by 1/sqrt(HD)*log2e)
  rope_scatter<<<dim3(QLEN, NHEAD), 128, 0, stream>>>(qkvF, 6144, 128, nullptr, maxp,
                                                      Qb, (long)QLEN * HD, 0, QSCALE);
  rope_scatter<<<dim3(QLEN, NKV), 128, 0, stream>>>(qkvF + 4096, 6144, 128, nullptr, maxp,
                                                    Kb, (long)KT_PAD * HD, CUR0, 1.0f);
  rope_scatter<<<dim3(NSINK, NKV), 128, 0, stream>>>(sink_k, 128, (long)NSINK * 128, sink_pos,
                                                     maxp, Kb, (long)KT_PAD * HD, 0, 1.0f);
  rope_scatter<<<dim3(NWIN, NKV), 128, 0, stream>>>(win_k, 128, (long)NWIN * 128, key_pos,
                                                    maxp, Kb, (long)KT_PAD * HD, NSINK, 1.0f);
  scatter_vt<<<dim3(1, 4, NKV), tb, 0, stream>>>(sink_v, 128, (long)NSINK * 128, VTb, 0, NSINK);
  scatter_vt<<<dim3(64, 4, NKV), tb, 0, stream>>>(win_v, 128, (long)NWIN * 128, VTb, NSINK, NWIN);
  scatter_vt<<<dim3(64, 4, NKV), tb, 0, stream>>>(qkvF + 5120, 6144, 128, VTb, CUR0, QLEN);
  pad_zero<<<(NKV * (KT_PAD - KTOT) * HD + 255) / 256, 256, 0, stream>>>(Kb, VTb);

  attn_kernel<<<dim3(QLEN / 128, NHEAD), 256, 0, stream>>>(Qb, Kb, VTb, bias, attn);

  // output projection
  gemm_bt<<<dim3(32, 16), 256, 0, stream>>>(attn, WoT, out, QLEN, DMODEL, DMODEL);
}

// Round 2
// 909.571 us; speedup vs baseline: 1.3097x; 1.3097x over previous
//
#include <hip/hip_runtime.h>

typedef __attribute__((ext_vector_type(8))) short short8;
typedef __attribute__((ext_vector_type(4))) float f32x4;
typedef __attribute__((ext_vector_type(4))) unsigned short us4;

#define DEV static __device__ __forceinline__

constexpr int QLEN = 2048;
constexpr int DMODEL = 4096;
constexpr int NHEAD = 32;
constexpr int NKV = 8;
constexpr int HD = 128;
constexpr int NSINK = 4;
constexpr int NWIN = 2048;
constexpr int CUR0 = NSINK + NWIN;     // 2052
constexpr int KTOT = CUR0 + QLEN;      // 4100
constexpr int KT_PAD = 4224;           // 66 * 64
constexpr float LOG2E = 1.4426950408889634f;
constexpr float NEGBIG = -1.0e30f;
constexpr float QSCALE = 0.08838834764831843f * LOG2E; // 1/sqrt(128) * log2(e)

DEV unsigned short f2bf(float f) {
  unsigned int u = __float_as_uint(f);
  u += 0x7fffu + ((u >> 16) & 1u);
  return (unsigned short)(u >> 16);
}

DEV void gld16(const void* g, void* l) {
  __builtin_amdgcn_global_load_lds((const __attribute__((address_space(1))) void*)g,
                                   (__attribute__((address_space(3))) void*)l, 16, 0, 0);
}

// ---------------- small prep kernels ----------------

__global__ void maxpos_kernel(const int* __restrict__ sp, const int* __restrict__ kp,
                              int* __restrict__ outp) {
  __shared__ int red[256];
  int t = threadIdx.x;
  int m = -0x7fffffff;
  for (int i = t; i < NSINK; i += 256) m = max(m, sp[i]);
  for (int i = t; i < NWIN; i += 256) m = max(m, kp[i]);
  red[t] = m;
  __syncthreads();
  for (int s = 128; s > 0; s >>= 1) {
    if (t < s) red[t] = max(red[t], red[t + s]);
    __syncthreads();
  }
  if (t == 0) outp[0] = red[0] + 1;
}

__global__ void bias_kernel(const float* __restrict__ sm, const float* __restrict__ km,
                            float* __restrict__ bias) {
  int kk = blockIdx.x * 256 + threadIdx.x;
  if (kk >= KT_PAD) return;
  float b;
  if (kk < NSINK) b = sm[kk] * NEGBIG;
  else if (kk < CUR0) b = km[kk - NSINK] * NEGBIG;
  else if (kk < KTOT) b = 0.0f;
  else b = NEGBIG;
  bias[kk] = b * LOG2E;
}

__global__ __launch_bounds__(256) void cvt_kernel(const float* __restrict__ src,
                                                  unsigned short* __restrict__ dst) {
  long i = ((long)blockIdx.x * 256 + threadIdx.x) * 4;
  f32x4 v = *(const f32x4*)(src + i);
  us4 o;
  o[0] = f2bf(v[0]); o[1] = f2bf(v[1]); o[2] = f2bf(v[2]); o[3] = f2bf(v[3]);
  *(us4*)(dst + i) = o;
}

// W [K][N] f32 -> WT [N][K] bf16
__global__ void transpose_cvt(const float* __restrict__ W, unsigned short* __restrict__ WT,
                              int K, int N) {
  __shared__ float t[32][33];
  int n0 = blockIdx.x * 32, k0 = blockIdx.y * 32;
  int tx = threadIdx.x, ty = threadIdx.y;
  for (int p = 0; p < 4; p++) {
    int k = k0 + ty + p * 8;
    t[ty + p * 8][tx] = W[(long)k * N + n0 + tx];
  }
  __syncthreads();
  for (int p = 0; p < 4; p++) {
    int n = n0 + ty + p * 8;
    WT[(long)n * K + k0 + tx] = f2bf(t[tx][ty + p * 8]);
  }
}

// ---------------- GEMM: C[M][N] f32 = A[M][K] bf16 @ Bt[N][K] bf16 ----------------
__global__ __launch_bounds__(256) void gemm_bt(const unsigned short* __restrict__ A,
                                               const unsigned short* __restrict__ Bt,
                                               float* __restrict__ C,
                                               int M, int N, int K) {
  __shared__ __align__(16) unsigned short As[128 * 64];
  __shared__ __align__(16) unsigned short Bs[128 * 64];
  int tid = threadIdx.x, lane = tid & 63, w = tid >> 6;
  int m0 = blockIdx.y * 128, n0 = blockIdx.x * 128;
  int wm = w & 1, wn = w >> 1;
  f32x4 z = {0.f, 0.f, 0.f, 0.f};
  f32x4 acc[4][4];
  for (int i = 0; i < 4; i++) for (int j = 0; j < 4; j++) acc[i][j] = z;
  int nK = K >> 6;
  for (int ks = 0; ks < nK; ks++) {
    long k0 = (long)ks << 6;
    for (int t = 0; t < 4; t++) {
      int chunk = w * 4 + t;
      int row = chunk * 8 + (lane >> 3);
      int kb = lane & 7;
      int kbs = kb ^ (row & 7);
      gld16(A + ((long)(m0 + row) * K + k0 + kbs * 8), &As[chunk * 512 + lane * 8]);
      gld16(Bt + ((long)(n0 + row) * K + k0 + kbs * 8), &Bs[chunk * 512 + lane * 8]);
    }
    __syncthreads();
    for (int kc = 0; kc < 2; kc++) {
      short8 af[4], bf[4];
      int c = kc * 4 + (lane >> 4);
      for (int i = 0; i < 4; i++) {
        int ra = wm * 64 + i * 16 + (lane & 15);
        af[i] = *(const short8*)&As[ra * 64 + (c ^ (ra & 7)) * 8];
        int rb = wn * 64 + i * 16 + (lane & 15);
        bf[i] = *(const short8*)&Bs[rb * 64 + (c ^ (rb & 7)) * 8];
      }
      for (int i = 0; i < 4; i++)
        for (int j = 0; j < 4; j++)
          acc[i][j] = __builtin_amdgcn_mfma_f32_16x16x32_bf16(af[i], bf[j], acc[i][j], 0, 0, 0);
    }
    __syncthreads();
  }
  for (int i = 0; i < 4; i++) {
    int m = m0 + wm * 64 + i * 16 + ((lane >> 4) << 2);
    for (int j = 0; j < 4; j++) {
      int n = n0 + wn * 64 + j * 16 + (lane & 15);
      float* cp = C + (long)m * N + n;
      for (int r = 0; r < 4; r++) cp[(long)r * N] = acc[i][j][r];
    }
  }
}

// ---------------- RoPE + scatter ----------------
__global__ void rope_scatter(const float* __restrict__ src, long sStride, long hStride,
                             const int* __restrict__ posArr, const int* __restrict__ maxp,
                             unsigned short* __restrict__ dst, long dstHStride, int dstPos0,
                             float scale) {
  int s = blockIdx.x, h = blockIdx.y, d = threadIdx.x;
  int pos = posArr ? posArr[s] : (maxp[0] + s);
  const float* row = src + (long)h * hStride + (long)s * sStride;
  float x = row[d];
  float x2 = row[d ^ 64];
  float rot = (d < 64) ? -x2 : x2;
  int i = d & 63;
  float invf = exp2f(-(float)(2 * i) * (13.287712379549449f / 128.0f));
  float ang = (float)pos * invf;
  float c = cosf(ang), sn = sinf(ang);
  float val = (x * c + rot * sn) * scale;
  dst[(long)h * dstHStride + (long)(dstPos0 + s) * HD + d] = f2bf(val);
}

__global__ void scatter_vt(const float* __restrict__ src, long sStride, long hStride,
                           unsigned short* __restrict__ VT, int dstPos0, int S) {
  __shared__ float t[32][33];
  int kvh = blockIdx.z, d0 = blockIdx.y * 32, s0 = blockIdx.x * 32;
  int tx = threadIdx.x, ty = threadIdx.y;
  for (int p = 0; p < 4; p++) {
    int s = s0 + ty + p * 8;
    if (s < S) t[ty + p * 8][tx] = src[(long)kvh * hStride + (long)s * sStride + d0 + tx];
  }
  __syncthreads();
  for (int p = 0; p < 4; p++) {
    int d = d0 + ty + p * 8;
    int s = s0 + tx;
    if (s < S)
      VT[((long)kvh * HD + d) * KT_PAD + dstPos0 + s] = f2bf(t[tx][ty + p * 8]);
  }
}

__global__ void pad_zero(unsigned short* __restrict__ Kb, unsigned short* __restrict__ VTb) {
  int idx = blockIdx.x * 256 + threadIdx.x;
  int total = NKV * (KT_PAD - KTOT) * HD;
  if (idx >= total) return;
  int per = (KT_PAD - KTOT) * HD;
  int kvh = idx / per;
  int rem = idx % per;
  int pos = KTOT + rem / HD;
  int d = rem % HD;
  Kb[((long)kvh * KT_PAD + pos) * HD + d] = 0;
  VTb[((long)kvh * HD + d) * KT_PAD + pos] = 0;
}

// ---------------- flash attention (S^T formulation) ----------------
// grid (16 qtile-pairs, 32 heads), 256 thr. Wave: 32 q rows (2 groups of 16). BK=64.
// S^T = K@Q^T puts each query's scores in a fixed lane column -> 4 shuffles per
// group per step instead of 64; P written as b64, read as aligned b128 A-frags.
__global__ __launch_bounds__(256) void attn_kernel(
    const unsigned short* __restrict__ Qb,   // [32][2048][128], pre-scaled by QSCALE
    const unsigned short* __restrict__ Kb,   // [8][KT_PAD][128]
    const unsigned short* __restrict__ VTb,  // [8][128][KT_PAD]
    const float* __restrict__ biasArr,       // [KT_PAD], already * LOG2E
    unsigned short* __restrict__ attnOut) {  // [2048][4096]
  __shared__ __align__(16) unsigned short Kt[64 * 128];     // [key][d], xor-swizzled
  __shared__ __align__(16) unsigned short Vt[128 * 64];     // [d][key], xor-swizzled
  __shared__ __align__(16) unsigned short Pl[4][2][16 * 72];// per wave/group [query][key+pad]
  __shared__ float abuf[4][2][16];
  int tid = threadIdx.x, lane = tid & 63, w = tid >> 6;
  int quad = lane >> 4, l15 = lane & 15;
  // heavy+light qtile pairing: blocks k and k+256 (same CU slot) sum to uniform work
  int qt = (blockIdx.y & 16) ? (15 - (int)blockIdx.x) : (int)blockIdx.x;
  int q0 = qt * 128;
  int h = blockIdx.y, kvh = h >> 2;
  int wq0 = q0 + w * 32;

  short8 qf[2][4];
  for (int g = 0; g < 2; g++)
    for (int kc = 0; kc < 4; kc++) {
      long off = ((long)h * QLEN + wq0 + g * 16 + l15) * HD + kc * 32 + quad * 8;
      qf[g][kc] = *(const short8*)(Qb + off);
    }

  f32x4 z = {0.f, 0.f, 0.f, 0.f};
  f32x4 o[2][8];
  for (int g = 0; g < 2; g++) for (int j = 0; j < 8; j++) o[g][j] = z;
  float mrun[2] = {-INFINITY, -INFINITY};
  float lrun[2] = {0.f, 0.f};

  int nsteps = min(KT_PAD / 64, (CUR0 + q0 + 127) / 64 + 1);
  const unsigned short* Kbase = Kb + (long)kvh * KT_PAD * HD;
  const unsigned short* Vbase = VTb + (long)kvh * HD * KT_PAD;

  for (int st = 0; st < nsteps; st++) {
    long k0 = (long)st * 64;
    for (int t = 0; t < 4; t++) {
      int chunk = w * 4 + t;
      { int row = chunk * 4 + quad;
        int kbs = l15 ^ (row & 15);
        gld16(Kbase + (k0 + row) * HD + kbs * 8, &Kt[chunk * 512 + lane * 8]); }
      { int row = chunk * 8 + (lane >> 3);
        int kbs = (lane & 7) ^ (row & 7);
        gld16(Vbase + (long)row * KT_PAD + k0 + kbs * 8, &Vt[chunk * 512 + lane * 8]); }
    }
    __syncthreads();

    f32x4 b4[4];
    for (int t = 0; t < 4; t++)
      b4[t] = *(const f32x4*)&biasArr[k0 + 16 * t + quad * 4];

    // S^T = K @ Q^T: A-frag from Kt rows (keys), B-frag = existing Q frags
    f32x4 stt[2][4];
    for (int g = 0; g < 2; g++) for (int t = 0; t < 4; t++) stt[g][t] = z;
    for (int kc = 0; kc < 4; kc++) {
      for (int t = 0; t < 4; t++) {
        int row = 16 * t + l15;
        short8 kf = *(const short8*)&Kt[row * 128 + (((kc * 4 + quad) ^ (row & 15))) * 8];
        stt[0][t] = __builtin_amdgcn_mfma_f32_16x16x32_bf16(kf, qf[0][kc], stt[0][t], 0, 0, 0);
        stt[1][t] = __builtin_amdgcn_mfma_f32_16x16x32_bf16(kf, qf[1][kc], stt[1][t], 0, 0, 0);
      }
    }

    for (int g = 0; g < 2; g++) {
      int query = wq0 + g * 16 + l15;
      float mx = -3.0e38f;
      for (int t = 0; t < 4; t++)
        for (int r = 0; r < 4; r++) {
          int key = (int)k0 + 16 * t + quad * 4 + r;
          float v = stt[g][t][r] + b4[t][r];
          if (key > query + CUR0) v = NEGBIG;
          stt[g][t][r] = v;
          mx = fmaxf(mx, v);
        }
      mx = fmaxf(mx, __shfl_xor(mx, 16, 64));
      mx = fmaxf(mx, __shfl_xor(mx, 32, 64));
      float mnew = fmaxf(mrun[g], mx);
      float alpha = exp2f(mrun[g] - mnew);
      mrun[g] = mnew;
      float ps = 0.f;
      for (int t = 0; t < 4; t++) {
        us4 pk;
        for (int r = 0; r < 4; r++) {
          float p = exp2f(stt[g][t][r] - mnew);
          ps += p;
          pk[r] = f2bf(p);
        }
        *(us4*)&Pl[w][g][l15 * 72 + 16 * t + quad * 4] = pk;
      }
      ps += __shfl_xor(ps, 16, 64);
      ps += __shfl_xor(ps, 32, 64);
      lrun[g] = lrun[g] * alpha + ps;
      if (lane < 16) abuf[w][g][lane] = alpha;
    }
    for (int g = 0; g < 2; g++) {
      f32x4 av = *(const f32x4*)&abuf[w][g][quad * 4];
      for (int jd = 0; jd < 8; jd++) o[g][jd] *= av;
    }

    // O += P @ V
    for (int c = 0; c < 2; c++) {
      short8 pf0 = *(const short8*)&Pl[w][0][l15 * 72 + c * 32 + quad * 8];
      short8 pf1 = *(const short8*)&Pl[w][1][l15 * 72 + c * 32 + quad * 8];
      for (int jd = 0; jd < 8; jd++) {
        int row = jd * 16 + l15;
        short8 vf = *(const short8*)&Vt[row * 64 + (((c * 4 + quad) ^ (row & 7))) * 8];
        o[0][jd] = __builtin_amdgcn_mfma_f32_16x16x32_bf16(pf0, vf, o[0][jd], 0, 0, 0);
        o[1][jd] = __builtin_amdgcn_mfma_f32_16x16x32_bf16(pf1, vf, o[1][jd], 0, 0, 0);
      }
    }
    __syncthreads();
  }

  for (int g = 0; g < 2; g++)
    if (lane < 16) abuf[w][g][lane] = 1.0f / lrun[g];
  for (int g = 0; g < 2; g++) {
    f32x4 lv = *(const f32x4*)&abuf[w][g][quad * 4];
    for (int r = 0; r < 4; r++) {
      int qrow = wq0 + g * 16 + quad * 4 + r;
      unsigned short* op = attnOut + (long)qrow * DMODEL + h * HD;
      for (int jd = 0; jd < 8; jd++) op[jd * 16 + l15] = f2bf(o[g][jd][r] * lv[r]);
    }
  }
}

// ---------------- launcher ----------------
extern "C" void kernel_launch(void* const* d_in, const int* in_sizes, int n_in,
                              void* d_out, int out_size, void* d_ws, size_t ws_size,
                              hipStream_t stream) {
  (void)in_sizes; (void)n_in; (void)out_size; (void)ws_size;
  const float* hidden    = (const float*)d_in[0];
  const float* sink_k    = (const float*)d_in[1];
  const float* sink_v    = (const float*)d_in[2];
  const float* win_k     = (const float*)d_in[3];
  const float* win_v     = (const float*)d_in[4];
  const int*   sink_pos  = (const int*)d_in[5];
  const int*   key_pos   = (const int*)d_in[6];
  const float* sink_mask = (const float*)d_in[7];
  const float* key_mask  = (const float*)d_in[8];
  const float* Wq = (const float*)d_in[9];
  const float* Wk = (const float*)d_in[10];
  const float* Wv = (const float*)d_in[11];
  const float* Wo = (const float*)d_in[12];
  float* out = (float*)d_out;

  char* ws = (char*)d_ws;
  unsigned short* hidB = (unsigned short*)(ws + 0);
  unsigned short* attn = (unsigned short*)(ws + 0);
  unsigned short* WoT  = (unsigned short*)(ws + 16777216L);
  unsigned short* WqT  = (unsigned short*)(ws + 50331648L);
  unsigned short* Qb   = (unsigned short*)(ws + 50331648L);
  unsigned short* Kb   = (unsigned short*)(ws + 50331648L + 16777216L);
  unsigned short* VTb  = (unsigned short*)(ws + 50331648L + 25427968L);
  unsigned short* WkT  = (unsigned short*)(ws + 50331648L + 33554432L);
  unsigned short* WvT  = (unsigned short*)(ws + 50331648L + 41943040L);
  float* qkvF = (float*)(ws + 100663296L);   // [2048][6144] f32
  float* bias = (float*)(ws + 150994944L);   // [KT_PAD] f32
  int*   maxp = (int*)(ws + 150994944L + 16896L);

  dim3 tb(32, 8);
  maxpos_kernel<<<1, 256, 0, stream>>>(sink_pos, key_pos, maxp);
  bias_kernel<<<(KT_PAD + 255) / 256, 256, 0, stream>>>(sink_mask, key_mask, bias);
  cvt_kernel<<<(QLEN * DMODEL / 4) / 256, 256, 0, stream>>>(hidden, hidB);
  transpose_cvt<<<dim3(128, 128), tb, 0, stream>>>(Wq, WqT, DMODEL, 4096);
  transpose_cvt<<<dim3(32, 128),  tb, 0, stream>>>(Wk, WkT, DMODEL, 1024);
  transpose_cvt<<<dim3(32, 128),  tb, 0, stream>>>(Wv, WvT, DMODEL, 1024);
  transpose_cvt<<<dim3(128, 128), tb, 0, stream>>>(Wo, WoT, DMODEL, 4096);

  gemm_bt<<<dim3(48, 16), 256, 0, stream>>>(hidB, WqT, qkvF, QLEN, 6144, DMODEL);

  rope_scatter<<<dim3(QLEN, NHEAD), 128, 0, stream>>>(qkvF, 6144, 128, nullptr, maxp,
                                                      Qb, (long)QLEN * HD, 0, QSCALE);
  rope_scatter<<<dim3(QLEN, NKV), 128, 0, stream>>>(qkvF + 4096, 6144, 128, nullptr, maxp,
                                                    Kb, (long)KT_PAD * HD, CUR0, 1.0f);
  rope_scatter<<<dim3(NSINK, NKV), 128, 0, stream>>>(sink_k, 128, (long)NSINK * 128, sink_pos,
                                                     maxp, Kb, (long)KT_PAD * HD, 0, 1.0f);
  rope_scatter<<<dim3(NWIN, NKV), 128, 0, stream>>>(win_k, 128, (long)NWIN * 128, key_pos,
                                                    maxp, Kb, (long)KT_PAD * HD, NSINK, 1.0f);
  scatter_vt<<<dim3(1, 4, NKV), tb, 0, stream>>>(sink_v, 128, (long)NSINK * 128, VTb, 0, NSINK);
  scatter_vt<<<dim3(64, 4, NKV), tb, 0, stream>>>(win_v, 128, (long)NWIN * 128, VTb, NSINK, NWIN);
  scatter_vt<<<dim3(64, 4, NKV), tb, 0, stream>>>(qkvF + 5120, 6144, 128, VTb, CUR0, QLEN);
  pad_zero<<<(NKV * (KT_PAD - KTOT) * HD + 255) / 256, 256, 0, stream>>>(Kb, VTb);

  attn_kernel<<<dim3(QLEN / 128, NHEAD), 256, 0, stream>>>(Qb, Kb, VTb, bias, attn);

  gemm_bt<<<dim3(32, 16), 256, 0, stream>>>(attn, WoT, out, QLEN, DMODEL, DMODEL);
}

// Round 3
// 853.299 us; speedup vs baseline: 1.3960x; 1.0659x over previous
//
#include <hip/hip_runtime.h>

typedef __attribute__((ext_vector_type(8))) short short8;
typedef __attribute__((ext_vector_type(4))) float f32x4;
typedef __attribute__((ext_vector_type(4))) unsigned short us4;

#define DEV static __device__ __forceinline__

constexpr int QLEN = 2048;
constexpr int DMODEL = 4096;
constexpr int NHEAD = 32;
constexpr int NKV = 8;
constexpr int HD = 128;
constexpr int NSINK = 4;
constexpr int NWIN = 2048;
constexpr int CUR0 = NSINK + NWIN;     // 2052
constexpr int KTOT = CUR0 + QLEN;      // 4100
constexpr int KT_PAD = 4224;           // 66 * 64
constexpr float LOG2E = 1.4426950408889634f;
constexpr float NEGBIG = -1.0e30f;
constexpr float QSCALE = 0.08838834764831843f * LOG2E; // 1/sqrt(128) * log2(e)

DEV unsigned short f2bf(float f) {
  unsigned int u = __float_as_uint(f);
  u += 0x7fffu + ((u >> 16) & 1u);
  return (unsigned short)(u >> 16);
}

DEV void gld16(const void* g, void* l) {
  __builtin_amdgcn_global_load_lds((const __attribute__((address_space(1))) void*)g,
                                   (__attribute__((address_space(3))) void*)l, 16, 0, 0);
}

// ---------------- small prep kernels ----------------

__global__ void maxpos_kernel(const int* __restrict__ sp, const int* __restrict__ kp,
                              int* __restrict__ outp) {
  __shared__ int red[256];
  int t = threadIdx.x;
  int m = -0x7fffffff;
  for (int i = t; i < NSINK; i += 256) m = max(m, sp[i]);
  for (int i = t; i < NWIN; i += 256) m = max(m, kp[i]);
  red[t] = m;
  __syncthreads();
  for (int s = 128; s > 0; s >>= 1) {
    if (t < s) red[t] = max(red[t], red[t + s]);
    __syncthreads();
  }
  if (t == 0) outp[0] = red[0] + 1;
}

__global__ void bias_kernel(const float* __restrict__ sm, const float* __restrict__ km,
                            float* __restrict__ bias) {
  int kk = blockIdx.x * 256 + threadIdx.x;
  if (kk >= KT_PAD) return;
  float b;
  if (kk < NSINK) b = sm[kk] * NEGBIG;
  else if (kk < CUR0) b = km[kk - NSINK] * NEGBIG;
  else if (kk < KTOT) b = 0.0f;
  else b = NEGBIG;
  bias[kk] = b * LOG2E;
}

__global__ __launch_bounds__(256) void cvt_kernel(const float* __restrict__ src,
                                                  unsigned short* __restrict__ dst) {
  long i = ((long)blockIdx.x * 256 + threadIdx.x) * 4;
  f32x4 v = *(const f32x4*)(src + i);
  us4 o;
  o[0] = f2bf(v[0]); o[1] = f2bf(v[1]); o[2] = f2bf(v[2]); o[3] = f2bf(v[3]);
  *(us4*)(dst + i) = o;
}

// W [K][N] f32 -> WT [N][K] bf16
__global__ void transpose_cvt(const float* __restrict__ W, unsigned short* __restrict__ WT,
                              int K, int N) {
  __shared__ float t[32][33];
  int n0 = blockIdx.x * 32, k0 = blockIdx.y * 32;
  int tx = threadIdx.x, ty = threadIdx.y;
  for (int p = 0; p < 4; p++) {
    int k = k0 + ty + p * 8;
    t[ty + p * 8][tx] = W[(long)k * N + n0 + tx];
  }
  __syncthreads();
  for (int p = 0; p < 4; p++) {
    int n = n0 + ty + p * 8;
    WT[(long)n * K + k0 + tx] = f2bf(t[tx][ty + p * 8]);
  }
}

// ---------------- GEMM: C[M][N] f32 = A[M][K] bf16 @ Bt[N][K] bf16 ----------------
__global__ __launch_bounds__(256) void gemm_bt(const unsigned short* __restrict__ A,
                                               const unsigned short* __restrict__ Bt,
                                               float* __restrict__ C,
                                               int M, int N, int K) {
  __shared__ __align__(16) unsigned short As[128 * 64];
  __shared__ __align__(16) unsigned short Bs[128 * 64];
  int tid = threadIdx.x, lane = tid & 63, w = tid >> 6;
  int m0 = blockIdx.y * 128, n0 = blockIdx.x * 128;
  int wm = w & 1, wn = w >> 1;
  f32x4 z = {0.f, 0.f, 0.f, 0.f};
  f32x4 acc[4][4];
  for (int i = 0; i < 4; i++) for (int j = 0; j < 4; j++) acc[i][j] = z;
  int nK = K >> 6;
  for (int ks = 0; ks < nK; ks++) {
    long k0 = (long)ks << 6;
    for (int t = 0; t < 4; t++) {
      int chunk = w * 4 + t;
      int row = chunk * 8 + (lane >> 3);
      int kb = lane & 7;
      int kbs = kb ^ (row & 7);
      gld16(A + ((long)(m0 + row) * K + k0 + kbs * 8), &As[chunk * 512 + lane * 8]);
      gld16(Bt + ((long)(n0 + row) * K + k0 + kbs * 8), &Bs[chunk * 512 + lane * 8]);
    }
    __syncthreads();
    for (int kc = 0; kc < 2; kc++) {
      short8 af[4], bf[4];
      int c = kc * 4 + (lane >> 4);
      for (int i = 0; i < 4; i++) {
        int ra = wm * 64 + i * 16 + (lane & 15);
        af[i] = *(const short8*)&As[ra * 64 + (c ^ (ra & 7)) * 8];
        int rb = wn * 64 + i * 16 + (lane & 15);
        bf[i] = *(const short8*)&Bs[rb * 64 + (c ^ (rb & 7)) * 8];
      }
      for (int i = 0; i < 4; i++)
        for (int j = 0; j < 4; j++)
          acc[i][j] = __builtin_amdgcn_mfma_f32_16x16x32_bf16(af[i], bf[j], acc[i][j], 0, 0, 0);
    }
    __syncthreads();
  }
  for (int i = 0; i < 4; i++) {
    int m = m0 + wm * 64 + i * 16 + ((lane >> 4) << 2);
    for (int j = 0; j < 4; j++) {
      int n = n0 + wn * 64 + j * 16 + (lane & 15);
      float* cp = C + (long)m * N + n;
      for (int r = 0; r < 4; r++) cp[(long)r * N] = acc[i][j][r];
    }
  }
}

// ---------------- RoPE + scatter ----------------
__global__ void rope_scatter(const float* __restrict__ src, long sStride, long hStride,
                             const int* __restrict__ posArr, const int* __restrict__ maxp,
                             unsigned short* __restrict__ dst, long dstHStride, int dstPos0,
                             float scale) {
  int s = blockIdx.x, h = blockIdx.y, d = threadIdx.x;
  int pos = posArr ? posArr[s] : (maxp[0] + s);
  const float* row = src + (long)h * hStride + (long)s * sStride;
  float x = row[d];
  float x2 = row[d ^ 64];
  float rot = (d < 64) ? -x2 : x2;
  int i = d & 63;
  float invf = exp2f(-(float)(2 * i) * (13.287712379549449f / 128.0f));
  float ang = (float)pos * invf;
  float c = cosf(ang), sn = sinf(ang);
  float val = (x * c + rot * sn) * scale;
  dst[(long)h * dstHStride + (long)(dstPos0 + s) * HD + d] = f2bf(val);
}

__global__ void scatter_vt(const float* __restrict__ src, long sStride, long hStride,
                           unsigned short* __restrict__ VT, int dstPos0, int S) {
  __shared__ float t[32][33];
  int kvh = blockIdx.z, d0 = blockIdx.y * 32, s0 = blockIdx.x * 32;
  int tx = threadIdx.x, ty = threadIdx.y;
  for (int p = 0; p < 4; p++) {
    int s = s0 + ty + p * 8;
    if (s < S) t[ty + p * 8][tx] = src[(long)kvh * hStride + (long)s * sStride + d0 + tx];
  }
  __syncthreads();
  for (int p = 0; p < 4; p++) {
    int d = d0 + ty + p * 8;
    int s = s0 + tx;
    if (s < S)
      VT[((long)kvh * HD + d) * KT_PAD + dstPos0 + s] = f2bf(t[tx][ty + p * 8]);
  }
}

__global__ void pad_zero(unsigned short* __restrict__ Kb, unsigned short* __restrict__ VTb) {
  int idx = blockIdx.x * 256 + threadIdx.x;
  int total = NKV * (KT_PAD - KTOT) * HD;
  if (idx >= total) return;
  int per = (KT_PAD - KTOT) * HD;
  int kvh = idx / per;
  int rem = idx % per;
  int pos = KTOT + rem / HD;
  int d = rem % HD;
  Kb[((long)kvh * KT_PAD + pos) * HD + d] = 0;
  VTb[((long)kvh * HD + d) * KT_PAD + pos] = 0;
}

// ---------------- flash attention (S^T, double-buffered, XCD-mapped) ----------------
DEV void stage_kv(const unsigned short* __restrict__ Kbase,
                  const unsigned short* __restrict__ Vbase, long k0,
                  unsigned short* KtB, unsigned short* VtB, int w, int lane) {
  int quad = lane >> 4, l15 = lane & 15;
  for (int t = 0; t < 4; t++) {
    int chunk = w * 4 + t;
    { int row = chunk * 4 + quad;
      int kbs = l15 ^ (row & 15);
      gld16(Kbase + (k0 + row) * HD + kbs * 8, &KtB[chunk * 512 + lane * 8]); }
    { int row = chunk * 8 + (lane >> 3);
      int kbs = (lane & 7) ^ (row & 7);
      gld16(Vbase + (long)row * KT_PAD + k0 + kbs * 8, &VtB[chunk * 512 + lane * 8]); }
  }
}

// grid (32 heads-remapped, 16 qtile-slots), 256 thr, 32 q/wave (2 groups of 16)
__global__ __launch_bounds__(256) void attn_kernel(
    const unsigned short* __restrict__ Qb,   // [32][2048][128], pre-scaled by QSCALE
    const unsigned short* __restrict__ Kb,   // [8][KT_PAD][128]
    const unsigned short* __restrict__ VTb,  // [8][128][KT_PAD]
    const float* __restrict__ biasArr,       // [KT_PAD], already * LOG2E
    unsigned short* __restrict__ attnOut) {  // [2048][4096]
  __shared__ __align__(16) unsigned short Kt[2][64 * 128];
  __shared__ __align__(16) unsigned short Vt[2][128 * 64];
  __shared__ __align__(16) unsigned short Pl[4][16 * 72];  // per-wave, reused per group
  __shared__ float abuf[4][2][16];
  int tid = threadIdx.x, lane = tid & 63, w = tid >> 6;
  int quad = lane >> 4, l15 = lane & 15;
  // XCD locality: x%8 selects kvh -> all 4 heads of a kvh land on one XCD (2.2MB < 4MB L2)
  int hh = blockIdx.x;
  int h = (hh & 7) * 4 + (hh >> 3);
  int kvh = hh & 7;
  // balance: CU-slot pair (y, y+8) -> qt sum = 15 (uniform causal work)
  int yt = blockIdx.y;
  int qt = (yt < 8) ? yt : (23 - yt);
  int q0 = qt * 128;
  int wq0 = q0 + w * 32;

  short8 qf[2][4];
  for (int g = 0; g < 2; g++)
    for (int kc = 0; kc < 4; kc++) {
      long off = ((long)h * QLEN + wq0 + g * 16 + l15) * HD + kc * 32 + quad * 8;
      qf[g][kc] = *(const short8*)(Qb + off);
    }

  f32x4 z = {0.f, 0.f, 0.f, 0.f};
  f32x4 o[2][8];
  for (int g = 0; g < 2; g++) for (int j = 0; j < 8; j++) o[g][j] = z;
  float mrun[2] = {-INFINITY, -INFINITY};
  float lrun[2] = {0.f, 0.f};

  int nsteps = min(KT_PAD / 64, (CUR0 + q0 + 127) / 64 + 1);
  const unsigned short* Kbase = Kb + (long)kvh * KT_PAD * HD;
  const unsigned short* Vbase = VTb + (long)kvh * HD * KT_PAD;

  stage_kv(Kbase, Vbase, 0, Kt[0], Vt[0], w, lane);

  for (int st = 0; st < nsteps; st++) {
    long k0 = (long)st * 64;
    int cur = st & 1;
    __syncthreads();   // drains prefetch issued a full step ago

    // bias first (so its vmcnt wait doesn't chain on the prefetch below)
    f32x4 b4[4];
    for (int t = 0; t < 4; t++)
      b4[t] = *(const f32x4*)&biasArr[k0 + 16 * t + quad * 4];

    if (st + 1 < nsteps)
      stage_kv(Kbase, Vbase, k0 + 64, Kt[cur ^ 1], Vt[cur ^ 1], w, lane);

    const unsigned short* KtB = Kt[cur];
    const unsigned short* VtB = Vt[cur];

    // S^T = K @ Q^T for both groups
    f32x4 stt[2][4];
    for (int g = 0; g < 2; g++) for (int t = 0; t < 4; t++) stt[g][t] = z;
    for (int kc = 0; kc < 4; kc++) {
      for (int t = 0; t < 4; t++) {
        int row = 16 * t + l15;
        short8 kf = *(const short8*)&KtB[row * 128 + (((kc * 4 + quad) ^ (row & 15))) * 8];
        stt[0][t] = __builtin_amdgcn_mfma_f32_16x16x32_bf16(kf, qf[0][kc], stt[0][t], 0, 0, 0);
        stt[1][t] = __builtin_amdgcn_mfma_f32_16x16x32_bf16(kf, qf[1][kc], stt[1][t], 0, 0, 0);
      }
    }

    for (int g = 0; g < 2; g++) {
      int query = wq0 + g * 16 + l15;
      bool needMask = (int)k0 + 63 > wq0 + g * 16 + CUR0;  // wave-uniform
      float mx = -3.0e38f;
      if (needMask) {
        for (int t = 0; t < 4; t++)
          for (int r = 0; r < 4; r++) {
            int key = (int)k0 + 16 * t + quad * 4 + r;
            float v = stt[g][t][r] + b4[t][r];
            if (key > query + CUR0) v = NEGBIG;
            stt[g][t][r] = v;
            mx = fmaxf(mx, v);
          }
      } else {
        for (int t = 0; t < 4; t++)
          for (int r = 0; r < 4; r++) {
            float v = stt[g][t][r] + b4[t][r];
            stt[g][t][r] = v;
            mx = fmaxf(mx, v);
          }
      }
      mx = fmaxf(mx, __shfl_xor(mx, 16, 64));
      mx = fmaxf(mx, __shfl_xor(mx, 32, 64));
      float mnew = fmaxf(mrun[g], mx);
      float alpha = exp2f(mrun[g] - mnew);
      mrun[g] = mnew;
      float ps = 0.f;
      for (int t = 0; t < 4; t++) {
        us4 pk;
        for (int r = 0; r < 4; r++) {
          float p = exp2f(stt[g][t][r] - mnew);
          ps += p;
          pk[r] = f2bf(p);
        }
        *(us4*)&Pl[w][l15 * 72 + 16 * t + quad * 4] = pk;
      }
      if (lane < 16) abuf[w][g][lane] = alpha;
      // read P frags (same-wave LDS in-order: reads complete before next g's writes)
      short8 pf[2];
      pf[0] = *(const short8*)&Pl[w][l15 * 72 + 0 * 32 + quad * 8];
      pf[1] = *(const short8*)&Pl[w][l15 * 72 + 1 * 32 + quad * 8];
      ps += __shfl_xor(ps, 16, 64);
      ps += __shfl_xor(ps, 32, 64);
      lrun[g] = lrun[g] * alpha + ps;
      f32x4 av = *(const f32x4*)&abuf[w][g][quad * 4];
      for (int jd = 0; jd < 8; jd++) o[g][jd] *= av;
      // O_g += P_g @ V  (MFMA pipe overlaps next group's softmax VALU)
      for (int c = 0; c < 2; c++) {
        for (int jd = 0; jd < 8; jd++) {
          int row = jd * 16 + l15;
          short8 vf = *(const short8*)&VtB[row * 64 + (((c * 4 + quad) ^ (row & 7))) * 8];
          o[g][jd] = __builtin_amdgcn_mfma_f32_16x16x32_bf16(pf[c], vf, o[g][jd], 0, 0, 0);
        }
      }
    }
  }

  for (int g = 0; g < 2; g++)
    if (lane < 16) abuf[w][g][lane] = 1.0f / lrun[g];
  for (int g = 0; g < 2; g++) {
    f32x4 lv = *(const f32x4*)&abuf[w][g][quad * 4];
    for (int r = 0; r < 4; r++) {
      int qrow = wq0 + g * 16 + quad * 4 + r;
      unsigned short* op = attnOut + (long)qrow * DMODEL + h * HD;
      for (int jd = 0; jd < 8; jd++) op[jd * 16 + l15] = f2bf(o[g][jd][r] * lv[r]);
    }
  }
}

// ---------------- launcher ----------------
extern "C" void kernel_launch(void* const* d_in, const int* in_sizes, int n_in,
                              void* d_out, int out_size, void* d_ws, size_t ws_size,
                              hipStream_t stream) {
  (void)in_sizes; (void)n_in; (void)out_size; (void)ws_size;
  const float* hidden    = (const float*)d_in[0];
  const float* sink_k    = (const float*)d_in[1];
  const float* sink_v    = (const float*)d_in[2];
  const float* win_k     = (const float*)d_in[3];
  const float* win_v     = (const float*)d_in[4];
  const int*   sink_pos  = (const int*)d_in[5];
  const int*   key_pos   = (const int*)d_in[6];
  const float* sink_mask = (const float*)d_in[7];
  const float* key_mask  = (const float*)d_in[8];
  const float* Wq = (const float*)d_in[9];
  const float* Wk = (const float*)d_in[10];
  const float* Wv = (const float*)d_in[11];
  const float* Wo = (const float*)d_in[12];
  float* out = (float*)d_out;

  char* ws = (char*)d_ws;
  unsigned short* hidB = (unsigned short*)(ws + 0);
  unsigned short* attn = (unsigned short*)(ws + 0);
  unsigned short* WoT  = (unsigned short*)(ws + 16777216L);
  unsigned short* WqT  = (unsigned short*)(ws + 50331648L);
  unsigned short* Qb   = (unsigned short*)(ws + 50331648L);
  unsigned short* Kb   = (unsigned short*)(ws + 50331648L + 16777216L);
  unsigned short* VTb  = (unsigned short*)(ws + 50331648L + 25427968L);
  unsigned short* WkT  = (unsigned short*)(ws + 50331648L + 33554432L);
  unsigned short* WvT  = (unsigned short*)(ws + 50331648L + 41943040L);
  float* qkvF = (float*)(ws + 100663296L);   // [2048][6144] f32
  float* bias = (float*)(ws + 150994944L);   // [KT_PAD] f32
  int*   maxp = (int*)(ws + 150994944L + 16896L);

  dim3 tb(32, 8);
  maxpos_kernel<<<1, 256, 0, stream>>>(sink_pos, key_pos, maxp);
  bias_kernel<<<(KT_PAD + 255) / 256, 256, 0, stream>>>(sink_mask, key_mask, bias);
  cvt_kernel<<<(QLEN * DMODEL / 4) / 256, 256, 0, stream>>>(hidden, hidB);
  transpose_cvt<<<dim3(128, 128), tb, 0, stream>>>(Wq, WqT, DMODEL, 4096);
  transpose_cvt<<<dim3(32, 128),  tb, 0, stream>>>(Wk, WkT, DMODEL, 1024);
  transpose_cvt<<<dim3(32, 128),  tb, 0, stream>>>(Wv, WvT, DMODEL, 1024);
  transpose_cvt<<<dim3(128, 128), tb, 0, stream>>>(Wo, WoT, DMODEL, 4096);

  gemm_bt<<<dim3(48, 16), 256, 0, stream>>>(hidB, WqT, qkvF, QLEN, 6144, DMODEL);

  rope_scatter<<<dim3(QLEN, NHEAD), 128, 0, stream>>>(qkvF, 6144, 128, nullptr, maxp,
                                                      Qb, (long)QLEN * HD, 0, QSCALE);
  rope_scatter<<<dim3(QLEN, NKV), 128, 0, stream>>>(qkvF + 4096, 6144, 128, nullptr, maxp,
                                                    Kb, (long)KT_PAD * HD, CUR0, 1.0f);
  rope_scatter<<<dim3(NSINK, NKV), 128, 0, stream>>>(sink_k, 128, (long)NSINK * 128, sink_pos,
                                                     maxp, Kb, (long)KT_PAD * HD, 0, 1.0f);
  rope_scatter<<<dim3(NWIN, NKV), 128, 0, stream>>>(win_k, 128, (long)NWIN * 128, key_pos,
                                                    maxp, Kb, (long)KT_PAD * HD, NSINK, 1.0f);
  scatter_vt<<<dim3(1, 4, NKV), tb, 0, stream>>>(sink_v, 128, (long)NSINK * 128, VTb, 0, NSINK);
  scatter_vt<<<dim3(64, 4, NKV), tb, 0, stream>>>(win_v, 128, (long)NWIN * 128, VTb, NSINK, NWIN);
  scatter_vt<<<dim3(64, 4, NKV), tb, 0, stream>>>(qkvF + 5120, 6144, 128, VTb, CUR0, QLEN);
  pad_zero<<<(NKV * (KT_PAD - KTOT) * HD + 255) / 256, 256, 0, stream>>>(Kb, VTb);

  attn_kernel<<<dim3(32, 16), 256, 0, stream>>>(Qb, Kb, VTb, bias, attn);

  gemm_bt<<<dim3(32, 16), 256, 0, stream>>>(attn, WoT, out, QLEN, DMODEL, DMODEL);
}

// Round 4
// 774.130 us; speedup vs baseline: 1.5388x; 1.1023x over previous
//
#include <hip/hip_runtime.h>

typedef __attribute__((ext_vector_type(8))) short short8;
typedef __attribute__((ext_vector_type(4))) float f32x4;
typedef __attribute__((ext_vector_type(4))) unsigned short us4;

#define DEV static __device__ __forceinline__

constexpr int QLEN = 2048;
constexpr int DMODEL = 4096;
constexpr int NHEAD = 32;
constexpr int NKV = 8;
constexpr int HD = 128;
constexpr int NSINK = 4;
constexpr int NWIN = 2048;
constexpr int CUR0 = NSINK + NWIN;     // 2052
constexpr int KTOT = CUR0 + QLEN;      // 4100
constexpr int KT_PAD = 4224;           // 66 * 64
constexpr float LOG2E = 1.4426950408889634f;
constexpr float NEGBIG = -1.0e30f;
constexpr float MSHIFT = 32.0f;        // fixed softmax shift (log2 units)
constexpr float QSCALE = 0.08838834764831843f * LOG2E; // 1/sqrt(128) * log2(e)

DEV unsigned short f2bf(float f) {
  unsigned int u = __float_as_uint(f);
  u += 0x7fffu + ((u >> 16) & 1u);
  return (unsigned short)(u >> 16);
}

DEV void gld16(const void* g, void* l) {
  __builtin_amdgcn_global_load_lds((const __attribute__((address_space(1))) void*)g,
                                   (__attribute__((address_space(3))) void*)l, 16, 0, 0);
}

// ---------------- small prep kernels ----------------

__global__ void maxpos_kernel(const int* __restrict__ sp, const int* __restrict__ kp,
                              int* __restrict__ outp) {
  __shared__ int red[256];
  int t = threadIdx.x;
  int m = -0x7fffffff;
  for (int i = t; i < NSINK; i += 256) m = max(m, sp[i]);
  for (int i = t; i < NWIN; i += 256) m = max(m, kp[i]);
  red[t] = m;
  __syncthreads();
  for (int s = 128; s > 0; s >>= 1) {
    if (t < s) red[t] = max(red[t], red[t + s]);
    __syncthreads();
  }
  if (t == 0) outp[0] = red[0] + 1;
}

// bias' = mask*NEGBIG*log2e - MSHIFT for valid keys; NEGBIG for padding
__global__ void bias_kernel(const float* __restrict__ sm, const float* __restrict__ km,
                            float* __restrict__ bias) {
  int kk = blockIdx.x * 256 + threadIdx.x;
  if (kk >= KT_PAD) return;
  float b;
  if (kk < NSINK) b = sm[kk] * NEGBIG * LOG2E - MSHIFT;
  else if (kk < CUR0) b = km[kk - NSINK] * NEGBIG * LOG2E - MSHIFT;
  else if (kk < KTOT) b = -MSHIFT;
  else b = NEGBIG;
  bias[kk] = b;
}

__global__ __launch_bounds__(256) void cvt_kernel(const float* __restrict__ src,
                                                  unsigned short* __restrict__ dst) {
  long i = ((long)blockIdx.x * 256 + threadIdx.x) * 4;
  f32x4 v = *(const f32x4*)(src + i);
  us4 o;
  o[0] = f2bf(v[0]); o[1] = f2bf(v[1]); o[2] = f2bf(v[2]); o[3] = f2bf(v[3]);
  *(us4*)(dst + i) = o;
}

// W [K][N] f32 -> WT [N][K] bf16
__global__ void transpose_cvt(const float* __restrict__ W, unsigned short* __restrict__ WT,
                              int K, int N) {
  __shared__ float t[32][33];
  int n0 = blockIdx.x * 32, k0 = blockIdx.y * 32;
  int tx = threadIdx.x, ty = threadIdx.y;
  for (int p = 0; p < 4; p++) {
    int k = k0 + ty + p * 8;
    t[ty + p * 8][tx] = W[(long)k * N + n0 + tx];
  }
  __syncthreads();
  for (int p = 0; p < 4; p++) {
    int n = n0 + ty + p * 8;
    WT[(long)n * K + k0 + tx] = f2bf(t[tx][ty + p * 8]);
  }
}

// ---------------- GEMM: C[M][N] f32 = A[M][K] bf16 @ Bt[N][K] bf16 ----------------
__global__ __launch_bounds__(256) void gemm_bt(const unsigned short* __restrict__ A,
                                               const unsigned short* __restrict__ Bt,
                                               float* __restrict__ C,
                                               int M, int N, int K) {
  __shared__ __align__(16) unsigned short As[128 * 64];
  __shared__ __align__(16) unsigned short Bs[128 * 64];
  int tid = threadIdx.x, lane = tid & 63, w = tid >> 6;
  int m0 = blockIdx.y * 128, n0 = blockIdx.x * 128;
  int wm = w & 1, wn = w >> 1;
  f32x4 z = {0.f, 0.f, 0.f, 0.f};
  f32x4 acc[4][4];
  for (int i = 0; i < 4; i++) for (int j = 0; j < 4; j++) acc[i][j] = z;
  int nK = K >> 6;
  for (int ks = 0; ks < nK; ks++) {
    long k0 = (long)ks << 6;
    for (int t = 0; t < 4; t++) {
      int chunk = w * 4 + t;
      int row = chunk * 8 + (lane >> 3);
      int kb = lane & 7;
      int kbs = kb ^ (row & 7);
      gld16(A + ((long)(m0 + row) * K + k0 + kbs * 8), &As[chunk * 512 + lane * 8]);
      gld16(Bt + ((long)(n0 + row) * K + k0 + kbs * 8), &Bs[chunk * 512 + lane * 8]);
    }
    __syncthreads();
    for (int kc = 0; kc < 2; kc++) {
      short8 af[4], bf[4];
      int c = kc * 4 + (lane >> 4);
      for (int i = 0; i < 4; i++) {
        int ra = wm * 64 + i * 16 + (lane & 15);
        af[i] = *(const short8*)&As[ra * 64 + (c ^ (ra & 7)) * 8];
        int rb = wn * 64 + i * 16 + (lane & 15);
        bf[i] = *(const short8*)&Bs[rb * 64 + (c ^ (rb & 7)) * 8];
      }
      for (int i = 0; i < 4; i++)
        for (int j = 0; j < 4; j++)
          acc[i][j] = __builtin_amdgcn_mfma_f32_16x16x32_bf16(af[i], bf[j], acc[i][j], 0, 0, 0);
    }
    __syncthreads();
  }
  for (int i = 0; i < 4; i++) {
    int m = m0 + wm * 64 + i * 16 + ((lane >> 4) << 2);
    for (int j = 0; j < 4; j++) {
      int n = n0 + wn * 64 + j * 16 + (lane & 15);
      float* cp = C + (long)m * N + n;
      for (int r = 0; r < 4; r++) cp[(long)r * N] = acc[i][j][r];
    }
  }
}

// ---------------- RoPE + scatter ----------------
__global__ void rope_scatter(const float* __restrict__ src, long sStride, long hStride,
                             const int* __restrict__ posArr, const int* __restrict__ maxp,
                             unsigned short* __restrict__ dst, long dstHStride, int dstPos0,
                             float scale) {
  int s = blockIdx.x, h = blockIdx.y, d = threadIdx.x;
  int pos = posArr ? posArr[s] : (maxp[0] + s);
  const float* row = src + (long)h * hStride + (long)s * sStride;
  float x = row[d];
  float x2 = row[d ^ 64];
  float rot = (d < 64) ? -x2 : x2;
  int i = d & 63;
  float invf = exp2f(-(float)(2 * i) * (13.287712379549449f / 128.0f));
  float ang = (float)pos * invf;
  float c = __cosf(ang), sn = __sinf(ang);
  float val = (x * c + rot * sn) * scale;
  dst[(long)h * dstHStride + (long)(dstPos0 + s) * HD + d] = f2bf(val);
}

__global__ void scatter_vt(const float* __restrict__ src, long sStride, long hStride,
                           unsigned short* __restrict__ VT, int dstPos0, int S) {
  __shared__ float t[32][33];
  int kvh = blockIdx.z, d0 = blockIdx.y * 32, s0 = blockIdx.x * 32;
  int tx = threadIdx.x, ty = threadIdx.y;
  for (int p = 0; p < 4; p++) {
    int s = s0 + ty + p * 8;
    if (s < S) t[ty + p * 8][tx] = src[(long)kvh * hStride + (long)s * sStride + d0 + tx];
  }
  __syncthreads();
  for (int p = 0; p < 4; p++) {
    int d = d0 + ty + p * 8;
    int s = s0 + tx;
    if (s < S)
      VT[((long)kvh * HD + d) * KT_PAD + dstPos0 + s] = f2bf(t[tx][ty + p * 8]);
  }
}

__global__ void pad_zero(unsigned short* __restrict__ Kb, unsigned short* __restrict__ VTb) {
  int idx = blockIdx.x * 256 + threadIdx.x;
  int total = NKV * (KT_PAD - KTOT) * HD;
  if (idx >= total) return;
  int per = (KT_PAD - KTOT) * HD;
  int kvh = idx / per;
  int rem = idx % per;
  int pos = KTOT + rem / HD;
  int d = rem % HD;
  Kb[((long)kvh * KT_PAD + pos) * HD + d] = 0;
  VTb[((long)kvh * HD + d) * KT_PAD + pos] = 0;
}

// ---------------- flash attention (S^T, fixed-shift softmax, dbuf, XCD-mapped) ----
DEV void stage_kv(const unsigned short* __restrict__ Kbase,
                  const unsigned short* __restrict__ Vbase, long k0,
                  unsigned short* KtB, unsigned short* VtB, int w, int lane) {
  int quad = lane >> 4, l15 = lane & 15;
  for (int t = 0; t < 4; t++) {
    int chunk = w * 4 + t;
    { int row = chunk * 4 + quad;
      int kbs = l15 ^ (row & 15);
      gld16(Kbase + (k0 + row) * HD + kbs * 8, &KtB[chunk * 512 + lane * 8]); }
    { int row = chunk * 8 + (lane >> 3);
      int kbs = (lane & 7) ^ (row & 7);
      gld16(Vbase + (long)row * KT_PAD + k0 + kbs * 8, &VtB[chunk * 512 + lane * 8]); }
  }
}

// grid (32 heads-remapped, 16 qtile-slots), 256 thr, 32 q/wave (2 groups of 16)
__global__ __launch_bounds__(256) void attn_kernel(
    const unsigned short* __restrict__ Qb,   // [32][2048][128], pre-scaled by QSCALE
    const unsigned short* __restrict__ Kb,   // [8][KT_PAD][128]
    const unsigned short* __restrict__ VTb,  // [8][128][KT_PAD]
    const float* __restrict__ biasArr,       // [KT_PAD], log2-units incl. -MSHIFT
    unsigned short* __restrict__ attnOut) {  // [2048][4096]
  __shared__ __align__(16) unsigned short Kt[2][64 * 128];
  __shared__ __align__(16) unsigned short Vt[2][128 * 64];
  __shared__ __align__(16) unsigned short Pl[4][16 * 72];
  __shared__ float abuf[4][2][16];
  int tid = threadIdx.x, lane = tid & 63, w = tid >> 6;
  int quad = lane >> 4, l15 = lane & 15;
  int hh = blockIdx.x;
  int h = (hh & 7) * 4 + (hh >> 3);
  int kvh = hh & 7;
  int yt = blockIdx.y;
  int qt = (yt < 8) ? yt : (23 - yt);
  int q0 = qt * 128;
  int wq0 = q0 + w * 32;

  short8 qf[2][4];
  for (int g = 0; g < 2; g++)
    for (int kc = 0; kc < 4; kc++) {
      long off = ((long)h * QLEN + wq0 + g * 16 + l15) * HD + kc * 32 + quad * 8;
      qf[g][kc] = *(const short8*)(Qb + off);
    }

  f32x4 z = {0.f, 0.f, 0.f, 0.f};
  f32x4 o[2][8];
  for (int g = 0; g < 2; g++) for (int j = 0; j < 8; j++) o[g][j] = z;
  float lrun[2] = {0.f, 0.f};   // per-lane partial (this quad's keys); reduced at end

  int nsteps = min(KT_PAD / 64, (CUR0 + q0 + 127) / 64 + 1);
  const unsigned short* Kbase = Kb + (long)kvh * KT_PAD * HD;
  const unsigned short* Vbase = VTb + (long)kvh * HD * KT_PAD;

  stage_kv(Kbase, Vbase, 0, Kt[0], Vt[0], w, lane);

  for (int st = 0; st < nsteps; st++) {
    long k0 = (long)st * 64;
    int cur = st & 1;
    __syncthreads();

    f32x4 b4[4];
    for (int t = 0; t < 4; t++)
      b4[t] = *(const f32x4*)&biasArr[k0 + 16 * t + quad * 4];

    if (st + 1 < nsteps)
      stage_kv(Kbase, Vbase, k0 + 64, Kt[cur ^ 1], Vt[cur ^ 1], w, lane);

    const unsigned short* KtB = Kt[cur];
    const unsigned short* VtB = Vt[cur];

    f32x4 stt[2][4];
    for (int g = 0; g < 2; g++) for (int t = 0; t < 4; t++) stt[g][t] = z;
    for (int kc = 0; kc < 4; kc++) {
      for (int t = 0; t < 4; t++) {
        int row = 16 * t + l15;
        short8 kf = *(const short8*)&KtB[row * 128 + (((kc * 4 + quad) ^ (row & 15))) * 8];
        stt[0][t] = __builtin_amdgcn_mfma_f32_16x16x32_bf16(kf, qf[0][kc], stt[0][t], 0, 0, 0);
        stt[1][t] = __builtin_amdgcn_mfma_f32_16x16x32_bf16(kf, qf[1][kc], stt[1][t], 0, 0, 0);
      }
    }

    for (int g = 0; g < 2; g++) {
      // group fully beyond causal horizon -> all p = 0, skip (wave-uniform)
      if ((int)k0 > wq0 + g * 16 + 15 + CUR0) continue;
      int query = wq0 + g * 16 + l15;
      bool needMask = (int)k0 + 63 > wq0 + g * 16 + CUR0;  // wave-uniform
      float ps = 0.f;
      if (needMask) {
        for (int t = 0; t < 4; t++) {
          us4 pk;
          for (int r = 0; r < 4; r++) {
            int key = (int)k0 + 16 * t + quad * 4 + r;
            float v = stt[g][t][r] + b4[t][r];
            if (key > query + CUR0) v = NEGBIG;
            float p = exp2f(v);
            ps += p;
            pk[r] = f2bf(p);
          }
          *(us4*)&Pl[w][l15 * 72 + 16 * t + quad * 4] = pk;
        }
      } else {
        for (int t = 0; t < 4; t++) {
          us4 pk;
          for (int r = 0; r < 4; r++) {
            float p = exp2f(stt[g][t][r] + b4[t][r]);
            ps += p;
            pk[r] = f2bf(p);
          }
          *(us4*)&Pl[w][l15 * 72 + 16 * t + quad * 4] = pk;
        }
      }
      lrun[g] += ps;
      short8 pf[2];
      pf[0] = *(const short8*)&Pl[w][l15 * 72 + 0 * 32 + quad * 8];
      pf[1] = *(const short8*)&Pl[w][l15 * 72 + 1 * 32 + quad * 8];
      for (int c = 0; c < 2; c++) {
        for (int jd = 0; jd < 8; jd++) {
          int row = jd * 16 + l15;
          short8 vf = *(const short8*)&VtB[row * 64 + (((c * 4 + quad) ^ (row & 7))) * 8];
          o[g][jd] = __builtin_amdgcn_mfma_f32_16x16x32_bf16(pf[c], vf, o[g][jd], 0, 0, 0);
        }
      }
    }
  }

  // one-time l reduction across quads, then normalize + store
  for (int g = 0; g < 2; g++) {
    float l = lrun[g];
    l += __shfl_xor(l, 16, 64);
    l += __shfl_xor(l, 32, 64);
    if (lane < 16) abuf[w][g][lane] = 1.0f / l;
  }
  for (int g = 0; g < 2; g++) {
    f32x4 lv = *(const f32x4*)&abuf[w][g][quad * 4];
    for (int r = 0; r < 4; r++) {
      int qrow = wq0 + g * 16 + quad * 4 + r;
      unsigned short* op = attnOut + (long)qrow * DMODEL + h * HD;
      for (int jd = 0; jd < 8; jd++) op[jd * 16 + l15] = f2bf(o[g][jd][r] * lv[r]);
    }
  }
}

// ---------------- launcher ----------------
extern "C" void kernel_launch(void* const* d_in, const int* in_sizes, int n_in,
                              void* d_out, int out_size, void* d_ws, size_t ws_size,
                              hipStream_t stream) {
  (void)in_sizes; (void)n_in; (void)out_size; (void)ws_size;
  const float* hidden    = (const float*)d_in[0];
  const float* sink_k    = (const float*)d_in[1];
  const float* sink_v    = (const float*)d_in[2];
  const float* win_k     = (const float*)d_in[3];
  const float* win_v     = (const float*)d_in[4];
  const int*   sink_pos  = (const int*)d_in[5];
  const int*   key_pos   = (const int*)d_in[6];
  const float* sink_mask = (const float*)d_in[7];
  const float* key_mask  = (const float*)d_in[8];
  const float* Wq = (const float*)d_in[9];
  const float* Wk = (const float*)d_in[10];
  const float* Wv = (const float*)d_in[11];
  const float* Wo = (const float*)d_in[12];
  float* out = (float*)d_out;

  char* ws = (char*)d_ws;
  unsigned short* hidB = (unsigned short*)(ws + 0);
  unsigned short* attn = (unsigned short*)(ws + 0);
  unsigned short* WoT  = (unsigned short*)(ws + 16777216L);
  unsigned short* WqT  = (unsigned short*)(ws + 50331648L);
  unsigned short* Qb   = (unsigned short*)(ws + 50331648L);
  unsigned short* Kb   = (unsigned short*)(ws + 50331648L + 16777216L);
  unsigned short* VTb  = (unsigned short*)(ws + 50331648L + 25427968L);
  unsigned short* WkT  = (unsigned short*)(ws + 50331648L + 33554432L);
  unsigned short* WvT  = (unsigned short*)(ws + 50331648L + 41943040L);
  float* qkvF = (float*)(ws + 100663296L);   // [2048][6144] f32
  float* bias = (float*)(ws + 150994944L);   // [KT_PAD] f32
  int*   maxp = (int*)(ws + 150994944L + 16896L);

  dim3 tb(32, 8);
  maxpos_kernel<<<1, 256, 0, stream>>>(sink_pos, key_pos, maxp);
  bias_kernel<<<(KT_PAD + 255) / 256, 256, 0, stream>>>(sink_mask, key_mask, bias);
  cvt_kernel<<<(QLEN * DMODEL / 4) / 256, 256, 0, stream>>>(hidden, hidB);
  transpose_cvt<<<dim3(128, 128), tb, 0, stream>>>(Wq, WqT, DMODEL, 4096);
  transpose_cvt<<<dim3(32, 128),  tb, 0, stream>>>(Wk, WkT, DMODEL, 1024);
  transpose_cvt<<<dim3(32, 128),  tb, 0, stream>>>(Wv, WvT, DMODEL, 1024);
  transpose_cvt<<<dim3(128, 128), tb, 0, stream>>>(Wo, WoT, DMODEL, 4096);

  gemm_bt<<<dim3(48, 16), 256, 0, stream>>>(hidB, WqT, qkvF, QLEN, 6144, DMODEL);

  rope_scatter<<<dim3(QLEN, NHEAD), 128, 0, stream>>>(qkvF, 6144, 128, nullptr, maxp,
                                                      Qb, (long)QLEN * HD, 0, QSCALE);
  rope_scatter<<<dim3(QLEN, NKV), 128, 0, stream>>>(qkvF + 4096, 6144, 128, nullptr, maxp,
                                                    Kb, (long)KT_PAD * HD, CUR0, 1.0f);
  rope_scatter<<<dim3(NSINK, NKV), 128, 0, stream>>>(sink_k, 128, (long)NSINK * 128, sink_pos,
                                                     maxp, Kb, (long)KT_PAD * HD, 0, 1.0f);
  rope_scatter<<<dim3(NWIN, NKV), 128, 0, stream>>>(win_k, 128, (long)NWIN * 128, key_pos,
                                                    maxp, Kb, (long)KT_PAD * HD, NSINK, 1.0f);
  scatter_vt<<<dim3(1, 4, NKV), tb, 0, stream>>>(sink_v, 128, (long)NSINK * 128, VTb, 0, NSINK);
  scatter_vt<<<dim3(64, 4, NKV), tb, 0, stream>>>(win_v, 128, (long)NWIN * 128, VTb, NSINK, NWIN);
  scatter_vt<<<dim3(64, 4, NKV), tb, 0, stream>>>(qkvF + 5120, 6144, 128, VTb, CUR0, QLEN);
  pad_zero<<<(NKV * (KT_PAD - KTOT) * HD + 255) / 256, 256, 0, stream>>>(Kb, VTb);

  attn_kernel<<<dim3(32, 16), 256, 0, stream>>>(Qb, Kb, VTb, bias, attn);

  gemm_bt<<<dim3(32, 16), 256, 0, stream>>>(attn, WoT, out, QLEN, DMODEL, DMODEL);
}

// Round 5
// 766.315 us; speedup vs baseline: 1.5545x; 1.0102x over previous
//
#include <hip/hip_runtime.h>
#include <hip/hip_bf16.h>

typedef __attribute__((ext_vector_type(8))) short short8;
typedef __attribute__((ext_vector_type(4))) float f32x4;
typedef __attribute__((ext_vector_type(4))) unsigned short us4;

#define DEV static __device__ __forceinline__

constexpr int QLEN = 2048;
constexpr int DMODEL = 4096;
constexpr int NHEAD = 32;
constexpr int NKV = 8;
constexpr int HD = 128;
constexpr int NSINK = 4;
constexpr int NWIN = 2048;
constexpr int CUR0 = NSINK + NWIN;     // 2052
constexpr int KTOT = CUR0 + QLEN;      // 4100
constexpr int KT_PAD = 4224;           // 66 * 64
constexpr float LOG2E = 1.4426950408889634f;
constexpr float NEGBIG = -1.0e30f;
constexpr float MSHIFT = 32.0f;        // fixed softmax shift (log2 units)
constexpr float QSCALE = 0.08838834764831843f * LOG2E; // 1/sqrt(128) * log2(e)

DEV unsigned short f2bf(float f) {
  unsigned int u = __float_as_uint(f);
  u += 0x7fffu + ((u >> 16) & 1u);
  return (unsigned short)(u >> 16);
}

DEV unsigned int pk2(float a, float b) {   // packed bf16 pair, RNE (v_cvt_pk_bf16_f32)
  __hip_bfloat162 h = __float22bfloat162_rn(make_float2(a, b));
  return *(unsigned int*)&h;
}

DEV void gld16(const void* g, void* l) {
  __builtin_amdgcn_global_load_lds((const __attribute__((address_space(1))) void*)g,
                                   (__attribute__((address_space(3))) void*)l, 16, 0, 0);
}

// ---------------- small prep kernels ----------------

__global__ void maxpos_kernel(const int* __restrict__ sp, const int* __restrict__ kp,
                              int* __restrict__ outp) {
  __shared__ int red[256];
  int t = threadIdx.x;
  int m = -0x7fffffff;
  for (int i = t; i < NSINK; i += 256) m = max(m, sp[i]);
  for (int i = t; i < NWIN; i += 256) m = max(m, kp[i]);
  red[t] = m;
  __syncthreads();
  for (int s = 128; s > 0; s >>= 1) {
    if (t < s) red[t] = max(red[t], red[t + s]);
    __syncthreads();
  }
  if (t == 0) outp[0] = red[0] + 1;
}

__global__ void bias_kernel(const float* __restrict__ sm, const float* __restrict__ km,
                            float* __restrict__ bias) {
  int kk = blockIdx.x * 256 + threadIdx.x;
  if (kk >= KT_PAD) return;
  float b;
  if (kk < NSINK) b = sm[kk] * NEGBIG * LOG2E - MSHIFT;
  else if (kk < CUR0) b = km[kk - NSINK] * NEGBIG * LOG2E - MSHIFT;
  else if (kk < KTOT) b = -MSHIFT;
  else b = NEGBIG;
  bias[kk] = b;
}

// cos/sin table for query positions: tab[q][j] = (cos,sin)((maxp+q) * invf(j))
__global__ void postab_kernel(const int* __restrict__ maxp, float2* __restrict__ tab) {
  int q = blockIdx.x, j = threadIdx.x;
  float pos = (float)(maxp[0] + q);
  float invf = exp2f(-(float)(2 * j) * (13.287712379549449f / 128.0f));
  float ang = pos * invf;
  tab[q * 64 + j] = make_float2(__cosf(ang), __sinf(ang));
}

__global__ __launch_bounds__(256) void cvt_kernel(const float* __restrict__ src,
                                                  unsigned short* __restrict__ dst) {
  long i = ((long)blockIdx.x * 256 + threadIdx.x) * 4;
  f32x4 v = *(const f32x4*)(src + i);
  us4 o;
  o[0] = f2bf(v[0]); o[1] = f2bf(v[1]); o[2] = f2bf(v[2]); o[3] = f2bf(v[3]);
  *(us4*)(dst + i) = o;
}

// all 4 weight transposes in one launch. x: [0,128)=Wq [128,160)=Wk [160,192)=Wv [192,320)=Wo
__global__ void transpose_all(const float* __restrict__ Wq, const float* __restrict__ Wk,
                              const float* __restrict__ Wv, const float* __restrict__ Wo,
                              unsigned short* __restrict__ WqkvT,
                              unsigned short* __restrict__ WoT) {
  __shared__ float t[32][33];
  int bx = blockIdx.x;
  const float* W; unsigned short* WT; int N; int xl;
  if (bx < 128)      { W = Wq; WT = WqkvT;                   N = 4096; xl = bx; }
  else if (bx < 160) { W = Wk; WT = WqkvT + 4096L * 4096;    N = 1024; xl = bx - 128; }
  else if (bx < 192) { W = Wv; WT = WqkvT + 5120L * 4096;    N = 1024; xl = bx - 160; }
  else               { W = Wo; WT = WoT;                     N = 4096; xl = bx - 192; }
  int n0 = xl * 32, k0 = blockIdx.y * 32;
  int tx = threadIdx.x, ty = threadIdx.y;
  for (int p = 0; p < 4; p++) {
    int k = k0 + ty + p * 8;
    t[ty + p * 8][tx] = W[(long)k * N + n0 + tx];
  }
  __syncthreads();
  for (int p = 0; p < 4; p++) {
    int n = n0 + ty + p * 8;
    WT[(long)n * 4096 + k0 + tx] = f2bf(t[tx][ty + p * 8]);
  }
}

// ---------------- generic GEMM (used for output projection, f32 C) ----------------
__global__ __launch_bounds__(256) void gemm_bt(const unsigned short* __restrict__ A,
                                               const unsigned short* __restrict__ Bt,
                                               float* __restrict__ C,
                                               int M, int N, int K) {
  __shared__ __align__(16) unsigned short As[128 * 64];
  __shared__ __align__(16) unsigned short Bs[128 * 64];
  int tid = threadIdx.x, lane = tid & 63, w = tid >> 6;
  int m0 = blockIdx.y * 128, n0 = blockIdx.x * 128;
  int wm = w & 1, wn = w >> 1;
  f32x4 z = {0.f, 0.f, 0.f, 0.f};
  f32x4 acc[4][4];
  for (int i = 0; i < 4; i++) for (int j = 0; j < 4; j++) acc[i][j] = z;
  int nK = K >> 6;
  for (int ks = 0; ks < nK; ks++) {
    long k0 = (long)ks << 6;
    for (int t = 0; t < 4; t++) {
      int chunk = w * 4 + t;
      int row = chunk * 8 + (lane >> 3);
      int kbs = (lane & 7) ^ (row & 7);
      gld16(A + ((long)(m0 + row) * K + k0 + kbs * 8), &As[chunk * 512 + lane * 8]);
      gld16(Bt + ((long)(n0 + row) * K + k0 + kbs * 8), &Bs[chunk * 512 + lane * 8]);
    }
    __syncthreads();
    for (int kc = 0; kc < 2; kc++) {
      short8 af[4], bf[4];
      int c = kc * 4 + (lane >> 4);
      for (int i = 0; i < 4; i++) {
        int ra = wm * 64 + i * 16 + (lane & 15);
        af[i] = *(const short8*)&As[ra * 64 + (c ^ (ra & 7)) * 8];
        int rb = wn * 64 + i * 16 + (lane & 15);
        bf[i] = *(const short8*)&Bs[rb * 64 + (c ^ (rb & 7)) * 8];
      }
      for (int i = 0; i < 4; i++)
        for (int j = 0; j < 4; j++)
          acc[i][j] = __builtin_amdgcn_mfma_f32_16x16x32_bf16(af[i], bf[j], acc[i][j], 0, 0, 0);
    }
    __syncthreads();
  }
  for (int i = 0; i < 4; i++) {
    int m = m0 + wm * 64 + i * 16 + ((lane >> 4) << 2);
    for (int j = 0; j < 4; j++) {
      int n = n0 + wn * 64 + j * 16 + (lane & 15);
      float* cp = C + (long)m * N + n;
      for (int r = 0; r < 4; r++) cp[(long)r * N] = acc[i][j][r];
    }
  }
}

// ---------------- fused QKV GEMM + RoPE + scatter epilogue ----------------
// A=[2048][4096] bf16, Bt=[6144][4096] bf16. C-tile 128x128 aligns with heads:
// nb<32 -> Q head nb (rope, *QSCALE -> Qb); nb in[32,40) -> K-cur kvh nb-32
// (rope -> Kb at CUR0+); nb>=40 -> V kvh nb-40 (transpose -> VTb at CUR0+).
__global__ __launch_bounds__(256) void gemm_qkv(const unsigned short* __restrict__ A,
                                                const unsigned short* __restrict__ Bt,
                                                const float2* __restrict__ postab,
                                                unsigned short* __restrict__ Qb,
                                                unsigned short* __restrict__ Kb,
                                                unsigned short* __restrict__ VTb) {
  __shared__ __align__(16) char smem[66 * 512];           // 33 KB: staging / epilogue union
  unsigned short* As = (unsigned short*)smem;             // 16 KB
  unsigned short* Bs = As + 8192;                         // 16 KB
  float* Cs = (float*)smem;                               // 64 x 129 f32 = 33024 B
  constexpr int K = 4096;
  int tid = threadIdx.x, lane = tid & 63, w = tid >> 6;
  int quad = lane >> 4, l15 = lane & 15;
  int m0 = blockIdx.y * 128, n0 = blockIdx.x * 128;
  int wm = w & 1, wn = w >> 1;
  f32x4 z = {0.f, 0.f, 0.f, 0.f};
  f32x4 acc[4][4];
  for (int i = 0; i < 4; i++) for (int j = 0; j < 4; j++) acc[i][j] = z;
  for (int ks = 0; ks < K / 64; ks++) {
    long k0 = (long)ks << 6;
    for (int t = 0; t < 4; t++) {
      int chunk = w * 4 + t;
      int row = chunk * 8 + (lane >> 3);
      int kbs = (lane & 7) ^ (row & 7);
      gld16(A + ((long)(m0 + row) * K + k0 + kbs * 8), &As[chunk * 512 + lane * 8]);
      gld16(Bt + ((long)(n0 + row) * K + k0 + kbs * 8), &Bs[chunk * 512 + lane * 8]);
    }
    __syncthreads();
    for (int kc = 0; kc < 2; kc++) {
      short8 af[4], bf[4];
      int c = kc * 4 + quad;
      for (int i = 0; i < 4; i++) {
        int ra = wm * 64 + i * 16 + l15;
        af[i] = *(const short8*)&As[ra * 64 + (c ^ (ra & 7)) * 8];
        int rb = wn * 64 + i * 16 + l15;
        bf[i] = *(const short8*)&Bs[rb * 64 + (c ^ (rb & 7)) * 8];
      }
      for (int i = 0; i < 4; i++)
        for (int j = 0; j < 4; j++)
          acc[i][j] = __builtin_amdgcn_mfma_f32_16x16x32_bf16(af[i], bf[j], acc[i][j], 0, 0, 0);
    }
    __syncthreads();
  }

  int nb = blockIdx.x;
  int part = (nb < 32) ? 0 : (nb < 40 ? 1 : 2);
  int hh = (part == 0) ? nb : (part == 1 ? nb - 32 : nb - 40);
  float scale = (part == 0) ? QSCALE : 1.0f;

  for (int pass = 0; pass < 2; pass++) {
    __syncthreads();
    if (wm == pass) {
      for (int i = 0; i < 4; i++)
        for (int j = 0; j < 4; j++)
          for (int r = 0; r < 4; r++)
            Cs[(i * 16 + quad * 4 + r) * 129 + wn * 64 + j * 16 + l15] = acc[i][j][r];
    }
    __syncthreads();
    if (part < 2) {
      if (tid < 128) {
        int r = tid & 63, hf = tid >> 6;
        int query = m0 + pass * 64 + r;
        const float2* tb = postab + query * 64;
        unsigned short* dst = (part == 0)
            ? Qb + ((long)hh * QLEN + query) * HD + hf * 64
            : Kb + ((long)hh * KT_PAD + CUR0 + query) * HD + hf * 64;
        for (int j = 0; j < 64; j += 4) {
          float v[4];
          for (int u = 0; u < 4; u++) {
            float2 cs = tb[j + u];
            int d = hf * 64 + j + u;
            float xa = Cs[r * 129 + d];
            float xb = Cs[r * 129 + (d ^ 64)];
            v[u] = (xa * cs.x + (hf ? xb : -xb) * cs.y) * scale;
          }
          uint2 o4;
          o4.x = pk2(v[0], v[1]);
          o4.y = pk2(v[2], v[3]);
          *(uint2*)(dst + j) = o4;
        }
      }
    } else {
      if (tid < 128) {
        int d = tid;
        unsigned short* dst = VTb + ((long)hh * HD + d) * KT_PAD + CUR0 + m0 + pass * 64;
        for (int m = 0; m < 64; m += 4) {
          uint2 o4;
          o4.x = pk2(Cs[m * 129 + d], Cs[(m + 1) * 129 + d]);
          o4.y = pk2(Cs[(m + 2) * 129 + d], Cs[(m + 3) * 129 + d]);
          *(uint2*)(dst + m) = o4;
        }
      }
    }
  }
}

// ---------------- cache (sink + window) RoPE / V scatter ----------------
__global__ void rope_cache(const float* __restrict__ sink_k, const float* __restrict__ win_k,
                           const int* __restrict__ sp, const int* __restrict__ kp,
                           unsigned short* __restrict__ Kb) {
  int s = blockIdx.x, kvh = blockIdx.y, d = threadIdx.x;
  const float* src; int pos;
  if (s < NSINK) { src = sink_k + ((long)kvh * NSINK + s) * HD; pos = sp[s]; }
  else           { src = win_k + ((long)kvh * NWIN + (s - NSINK)) * HD; pos = kp[s - NSINK]; }
  float x = src[d];
  float x2 = src[d ^ 64];
  float rot = (d < 64) ? -x2 : x2;
  int i = d & 63;
  float invf = exp2f(-(float)(2 * i) * (13.287712379549449f / 128.0f));
  float ang = (float)pos * invf;
  float c = __cosf(ang), sn = __sinf(ang);
  Kb[((long)kvh * KT_PAD + s) * HD + d] = f2bf(x * c + rot * sn);
}

// x<64: window chunk; x==64: sinks
__global__ void scatter_cache(const float* __restrict__ sink_v, const float* __restrict__ win_v,
                              unsigned short* __restrict__ VTb) {
  __shared__ float t[32][33];
  int kvh = blockIdx.z, d0 = blockIdx.y * 32;
  const float* src; int S, s0, dstPos0;
  if (blockIdx.x < 64) { src = win_v + (long)kvh * NWIN * HD; S = NWIN; s0 = blockIdx.x * 32; dstPos0 = NSINK; }
  else                 { src = sink_v + (long)kvh * NSINK * HD; S = NSINK; s0 = 0; dstPos0 = 0; }
  int tx = threadIdx.x, ty = threadIdx.y;
  for (int p = 0; p < 4; p++) {
    int s = s0 + ty + p * 8;
    if (s < S) t[ty + p * 8][tx] = src[(long)s * HD + d0 + tx];
  }
  __syncthreads();
  for (int p = 0; p < 4; p++) {
    int d = d0 + ty + p * 8;
    int s = s0 + tx;
    if (s < S)
      VTb[((long)kvh * HD + d) * KT_PAD + dstPos0 + s] = f2bf(t[tx][ty + p * 8]);
  }
}

__global__ void pad_zero(unsigned short* __restrict__ Kb, unsigned short* __restrict__ VTb) {
  int idx = blockIdx.x * 256 + threadIdx.x;
  int total = NKV * (KT_PAD - KTOT) * HD;
  if (idx >= total) return;
  int per = (KT_PAD - KTOT) * HD;
  int kvh = idx / per;
  int rem = idx % per;
  int pos = KTOT + rem / HD;
  int d = rem % HD;
  Kb[((long)kvh * KT_PAD + pos) * HD + d] = 0;
  VTb[((long)kvh * HD + d) * KT_PAD + pos] = 0;
}

// ---------------- flash attention (S^T, fixed-shift softmax, dbuf, XCD-mapped) ----
DEV void stage_kv(const unsigned short* __restrict__ Kbase,
                  const unsigned short* __restrict__ Vbase, long k0,
                  unsigned short* KtB, unsigned short* VtB, int w, int lane) {
  int quad = lane >> 4, l15 = lane & 15;
  for (int t = 0; t < 4; t++) {
    int chunk = w * 4 + t;
    { int row = chunk * 4 + quad;
      int kbs = l15 ^ (row & 15);
      gld16(Kbase + (k0 + row) * HD + kbs * 8, &KtB[chunk * 512 + lane * 8]); }
    { int row = chunk * 8 + (lane >> 3);
      int kbs = (lane & 7) ^ (row & 7);
      gld16(Vbase + (long)row * KT_PAD + k0 + kbs * 8, &VtB[chunk * 512 + lane * 8]); }
  }
}

__global__ __launch_bounds__(256) void attn_kernel(
    const unsigned short* __restrict__ Qb,
    const unsigned short* __restrict__ Kb,
    const unsigned short* __restrict__ VTb,
    const float* __restrict__ biasArr,
    unsigned short* __restrict__ attnOut) {
  __shared__ __align__(16) unsigned short Kt[2][64 * 128];
  __shared__ __align__(16) unsigned short Vt[2][128 * 64];
  __shared__ __align__(16) unsigned short Pl[4][16 * 72];
  __shared__ float abuf[4][2][16];
  int tid = threadIdx.x, lane = tid & 63, w = tid >> 6;
  int quad = lane >> 4, l15 = lane & 15;
  int hh = blockIdx.x;
  int h = (hh & 7) * 4 + (hh >> 3);
  int kvh = hh & 7;
  int yt = blockIdx.y;
  int qt = (yt < 8) ? yt : (23 - yt);
  int q0 = qt * 128;
  int wq0 = q0 + w * 32;

  short8 qf[2][4];
  for (int g = 0; g < 2; g++)
    for (int kc = 0; kc < 4; kc++) {
      long off = ((long)h * QLEN + wq0 + g * 16 + l15) * HD + kc * 32 + quad * 8;
      qf[g][kc] = *(const short8*)(Qb + off);
    }

  f32x4 z = {0.f, 0.f, 0.f, 0.f};
  f32x4 o[2][8];
  for (int g = 0; g < 2; g++) for (int j = 0; j < 8; j++) o[g][j] = z;
  float lrun[2] = {0.f, 0.f};

  int nsteps = min(KT_PAD / 64, (CUR0 + q0 + 127) / 64 + 1);
  const unsigned short* Kbase = Kb + (long)kvh * KT_PAD * HD;
  const unsigned short* Vbase = VTb + (long)kvh * HD * KT_PAD;

  stage_kv(Kbase, Vbase, 0, Kt[0], Vt[0], w, lane);

  for (int st = 0; st < nsteps; st++) {
    long k0 = (long)st * 64;
    int cur = st & 1;
    __syncthreads();

    f32x4 b4[4];
    for (int t = 0; t < 4; t++)
      b4[t] = *(const f32x4*)&biasArr[k0 + 16 * t + quad * 4];

    if (st + 1 < nsteps)
      stage_kv(Kbase, Vbase, k0 + 64, Kt[cur ^ 1], Vt[cur ^ 1], w, lane);

    const unsigned short* KtB = Kt[cur];
    const unsigned short* VtB = Vt[cur];

    f32x4 stt[2][4];
    for (int g = 0; g < 2; g++) for (int t = 0; t < 4; t++) stt[g][t] = z;
    for (int kc = 0; kc < 4; kc++) {
      for (int t = 0; t < 4; t++) {
        int row = 16 * t + l15;
        short8 kf = *(const short8*)&KtB[row * 128 + (((kc * 4 + quad) ^ (row & 15))) * 8];
        stt[0][t] = __builtin_amdgcn_mfma_f32_16x16x32_bf16(kf, qf[0][kc], stt[0][t], 0, 0, 0);
        stt[1][t] = __builtin_amdgcn_mfma_f32_16x16x32_bf16(kf, qf[1][kc], stt[1][t], 0, 0, 0);
      }
    }

    for (int g = 0; g < 2; g++) {
      if ((int)k0 > wq0 + g * 16 + 15 + CUR0) continue;
      int query = wq0 + g * 16 + l15;
      bool needMask = (int)k0 + 63 > wq0 + g * 16 + CUR0;
      float ps = 0.f;
      if (needMask) {
        for (int t = 0; t < 4; t++) {
          float p[4];
          for (int r = 0; r < 4; r++) {
            int key = (int)k0 + 16 * t + quad * 4 + r;
            float v = stt[g][t][r] + b4[t][r];
            if (key > query + CUR0) v = NEGBIG;
            p[r] = exp2f(v);
            ps += p[r];
          }
          uint2 pw;
          pw.x = pk2(p[0], p[1]);
          pw.y = pk2(p[2], p[3]);
          *(uint2*)&Pl[w][l15 * 72 + 16 * t + quad * 4] = pw;
        }
      } else {
        for (int t = 0; t < 4; t++) {
          float p[4];
          for (int r = 0; r < 4; r++) {
            p[r] = exp2f(stt[g][t][r] + b4[t][r]);
            ps += p[r];
          }
          uint2 pw;
          pw.x = pk2(p[0], p[1]);
          pw.y = pk2(p[2], p[3]);
          *(uint2*)&Pl[w][l15 * 72 + 16 * t + quad * 4] = pw;
        }
      }
      lrun[g] += ps;
      short8 pf[2];
      pf[0] = *(const short8*)&Pl[w][l15 * 72 + 0 * 32 + quad * 8];
      pf[1] = *(const short8*)&Pl[w][l15 * 72 + 1 * 32 + quad * 8];
      for (int c = 0; c < 2; c++) {
        for (int jd = 0; jd < 8; jd++) {
          int row = jd * 16 + l15;
          short8 vf = *(const short8*)&VtB[row * 64 + (((c * 4 + quad) ^ (row & 7))) * 8];
          o[g][jd] = __builtin_amdgcn_mfma_f32_16x16x32_bf16(pf[c], vf, o[g][jd], 0, 0, 0);
        }
      }
    }
  }

  for (int g = 0; g < 2; g++) {
    float l = lrun[g];
    l += __shfl_xor(l, 16, 64);
    l += __shfl_xor(l, 32, 64);
    if (lane < 16) abuf[w][g][lane] = 1.0f / l;
  }
  for (int g = 0; g < 2; g++) {
    f32x4 lv = *(const f32x4*)&abuf[w][g][quad * 4];
    for (int r = 0; r < 4; r++) {
      int qrow = wq0 + g * 16 + quad * 4 + r;
      unsigned short* op = attnOut + (long)qrow * DMODEL + h * HD;
      for (int jd = 0; jd < 8; jd++) op[jd * 16 + l15] = f2bf(o[g][jd][r] * lv[r]);
    }
  }
}

// ---------------- launcher ----------------
extern "C" void kernel_launch(void* const* d_in, const int* in_sizes, int n_in,
                              void* d_out, int out_size, void* d_ws, size_t ws_size,
                              hipStream_t stream) {
  (void)in_sizes; (void)n_in; (void)out_size; (void)ws_size;
  const float* hidden    = (const float*)d_in[0];
  const float* sink_k    = (const float*)d_in[1];
  const float* sink_v    = (const float*)d_in[2];
  const float* win_k     = (const float*)d_in[3];
  const float* win_v     = (const float*)d_in[4];
  const int*   sink_pos  = (const int*)d_in[5];
  const int*   key_pos   = (const int*)d_in[6];
  const float* sink_mask = (const float*)d_in[7];
  const float* key_mask  = (const float*)d_in[8];
  const float* Wq = (const float*)d_in[9];
  const float* Wk = (const float*)d_in[10];
  const float* Wv = (const float*)d_in[11];
  const float* Wo = (const float*)d_in[12];
  float* out = (float*)d_out;

  char* ws = (char*)d_ws;
  unsigned short* hidB  = (unsigned short*)(ws + 0);           // 16.8 MB; attn reuses
  unsigned short* attn  = (unsigned short*)(ws + 0);
  unsigned short* WoT   = (unsigned short*)(ws + 16777216L);   // 33.5 MB
  unsigned short* WqkvT = (unsigned short*)(ws + 50331648L);   // 50.3 MB
  unsigned short* Qb    = (unsigned short*)(ws + 100663296L);  // 16.8 MB
  unsigned short* Kb    = (unsigned short*)(ws + 117440512L);  // 8.65 MB
  unsigned short* VTb   = (unsigned short*)(ws + 126091264L);  // 8.65 MB
  float2* postab        = (float2*)(ws + 134742016L);          // 1 MB
  float* bias           = (float*)(ws + 135790592L);           // 16.9 KB
  int* maxp             = (int*)(ws + 135807488L);

  maxpos_kernel<<<1, 256, 0, stream>>>(sink_pos, key_pos, maxp);
  bias_kernel<<<(KT_PAD + 255) / 256, 256, 0, stream>>>(sink_mask, key_mask, bias);
  postab_kernel<<<QLEN, 64, 0, stream>>>(maxp, postab);
  cvt_kernel<<<(QLEN * DMODEL / 4) / 256, 256, 0, stream>>>(hidden, hidB);
  transpose_all<<<dim3(320, 128), dim3(32, 8), 0, stream>>>(Wq, Wk, Wv, Wo, WqkvT, WoT);

  gemm_qkv<<<dim3(48, 16), 256, 0, stream>>>(hidB, WqkvT, postab, Qb, Kb, VTb);

  rope_cache<<<dim3(CUR0, NKV), 128, 0, stream>>>(sink_k, win_k, sink_pos, key_pos, Kb);
  scatter_cache<<<dim3(65, 4, NKV), dim3(32, 8), 0, stream>>>(sink_v, win_v, VTb);
  pad_zero<<<(NKV * (KT_PAD - KTOT) * HD + 255) / 256, 256, 0, stream>>>(Kb, VTb);

  attn_kernel<<<dim3(32, 16), 256, 0, stream>>>(Qb, Kb, VTb, bias, attn);

  gemm_bt<<<dim3(32, 16), 256, 0, stream>>>(attn, WoT, out, QLEN, DMODEL, DMODEL);
}